// Round 4
// baseline (13794.608 us; speedup 1.0000x reference)
//
#include <hip/hip_runtime.h>
#include <hip/hip_bf16.h>
#include <math.h>

#define SE_    128
#define T_     256
#define B_     128
#define NH_    4
#define HD_    132
#define D_FEAT_ 1024
#define D_MODEL_ 528
#define D_FINAL_ 1040
#define D_FF_  128

typedef __hip_bfloat16 bf16;

__device__ __forceinline__ float toF(const float x){ return x; }
__device__ __forceinline__ float toF(const bf16 x){ return __bfloat162float(x); }
__device__ __forceinline__ void load4(const float* p, float f[4]){
  const float4 v = *reinterpret_cast<const float4*>(p);
  f[0]=v.x; f[1]=v.y; f[2]=v.z; f[3]=v.w;
}
// runtime-dtype read (wave-uniform flag)
__device__ __forceinline__ float rdIn(const void* p, long i, int f32){
  return f32 ? ((const float*)p)[i] : toF(((const bf16*)p)[i]);
}

// ---------------- dtype detect: 1 = f32 inputs, 0 = bf16 ----------------
__global__ void detect_k(const void* __restrict__ src, int* __restrict__ flag){
  const unsigned int* p = (const unsigned int*)src;
  int bad = 0;
  for (int i = threadIdx.x; i < 4096; i += 256){
    const unsigned int lo = p[i] & 0xFFFFu;
    const unsigned int e = (lo >> 7) & 0xFFu;
    if (e >= 0xC0u) bad++;
  }
  __shared__ int red[256];
  red[threadIdx.x] = bad; __syncthreads();
  for (int h = 128; h > 0; h >>= 1){
    if (threadIdx.x < h) red[threadIdx.x] += red[threadIdx.x+h];
    __syncthreads();
  }
  if (threadIdx.x == 0) *flag = (red[0] > 64) ? 1 : 0;
}

// ---------------- normalize input tensor -> f32 ----------------
__global__ void cvt_f32(const void* __restrict__ in, float* __restrict__ out, long n,
                        const int* __restrict__ flag){
  const long i = (long)blockIdx.x*256 + threadIdx.x;
  if (i >= n) return;
  out[i] = rdIn(in, i, *flag);
}

// ---------------- NT GEMM: C[m,n] = mult*sum_k A[m,k]*B[n,k] (+bias,relu,acc) ----------------
template<bool RELU, bool ACC>
__global__ __launch_bounds__(256) void gemm_nt(
    const float* __restrict__ Ag, const float* __restrict__ Bg,
    const float* __restrict__ bias, float* __restrict__ Cg,
    int M, int N, int K, long lda, long ldb, long ldc,
    long sA, long sB, long sC, float mult)
{
  __shared__ float As[16][68];
  __shared__ float Bs[16][68];
  const int tid = threadIdx.x;
  const int tx = tid & 15, ty = tid >> 4;
  const int m0 = blockIdx.y * 64, n0 = blockIdx.x * 64;
  const float* A = Ag + (long)blockIdx.z * sA;
  const float* B = Bg + (long)blockIdx.z * sB;
  float*       C = Cg + (long)blockIdx.z * sC;
  const int sr = tid >> 2;
  const int sk = (tid & 3) * 4;
  float acc[4][4] = {};

  for (int kb = 0; kb < K; kb += 16){
    {
      const int m = m0 + sr;
      if (m < M){
        if (kb + sk + 3 < K){
          float f[4]; load4(A + (long)m*lda + kb + sk, f);
          As[sk][sr]=f[0]; As[sk+1][sr]=f[1]; As[sk+2][sr]=f[2]; As[sk+3][sr]=f[3];
        } else {
          #pragma unroll
          for (int i=0;i<4;++i){ int k=kb+sk+i; As[sk+i][sr] = (k<K)? A[(long)m*lda+k] : 0.f; }
        }
      } else {
        #pragma unroll
        for (int i=0;i<4;++i) As[sk+i][sr]=0.f;
      }
      const int n = n0 + sr;
      if (n < N){
        if (kb + sk + 3 < K){
          float f[4]; load4(B + (long)n*ldb + kb + sk, f);
          Bs[sk][sr]=f[0]; Bs[sk+1][sr]=f[1]; Bs[sk+2][sr]=f[2]; Bs[sk+3][sr]=f[3];
        } else {
          #pragma unroll
          for (int i=0;i<4;++i){ int k=kb+sk+i; Bs[sk+i][sr] = (k<K)? B[(long)n*ldb+k] : 0.f; }
        }
      } else {
        #pragma unroll
        for (int i=0;i<4;++i) Bs[sk+i][sr]=0.f;
      }
    }
    __syncthreads();
    #pragma unroll
    for (int k=0;k<16;++k){
      float a[4], b[4];
      *reinterpret_cast<float4*>(a) = *reinterpret_cast<const float4*>(&As[k][ty*4]);
      *reinterpret_cast<float4*>(b) = *reinterpret_cast<const float4*>(&Bs[k][tx*4]);
      #pragma unroll
      for (int i=0;i<4;++i)
        #pragma unroll
        for (int j=0;j<4;++j)
          acc[i][j] = fmaf(a[i], b[j], acc[i][j]);
    }
    __syncthreads();
  }
  #pragma unroll
  for (int i=0;i<4;++i){
    const int m = m0 + ty*4 + i;
    if (m >= M) continue;
    #pragma unroll
    for (int j=0;j<4;++j){
      const int n = n0 + tx*4 + j;
      if (n >= N) continue;
      float v = acc[i][j] * mult;
      if (bias) v += bias[n];
      if (RELU) v = fmaxf(v, 0.f);
      const long idx = (long)m*ldc + n;
      if (ACC) v += C[idx];
      C[idx] = v;
    }
  }
}

// ---------------- NN GEMM: C[m,n] (+)= mult*sum_k A[m,k]*B[k,n] ----------------
template<bool ACC>
__global__ __launch_bounds__(256) void gemm_nn(
    const float* __restrict__ Ag, const float* __restrict__ Bg,
    float* __restrict__ Cg,
    int M, int N, int K, long lda, long ldb, long ldc,
    long sA, long sB, long sC, float mult)
{
  __shared__ float As[16][68];
  __shared__ float Bs[16][68];
  const int tid = threadIdx.x;
  const int tx = tid & 15, ty = tid >> 4;
  const int m0 = blockIdx.y * 64, n0 = blockIdx.x * 64;
  const float* A = Ag + (long)blockIdx.z * sA;
  const float* B = Bg + (long)blockIdx.z * sB;
  float*       C = Cg + (long)blockIdx.z * sC;
  const int sr = tid >> 2, sk = (tid & 3) * 4;
  const int br = tid >> 4, bc = (tid & 15) * 4;
  float acc[4][4] = {};

  for (int kb = 0; kb < K; kb += 16){
    {
      const int m = m0 + sr;
      if (m < M){
        if (kb + sk + 3 < K){
          float f[4]; load4(A + (long)m*lda + kb + sk, f);
          As[sk][sr]=f[0]; As[sk+1][sr]=f[1]; As[sk+2][sr]=f[2]; As[sk+3][sr]=f[3];
        } else {
          #pragma unroll
          for (int i=0;i<4;++i){ int k=kb+sk+i; As[sk+i][sr] = (k<K)? A[(long)m*lda+k] : 0.f; }
        }
      } else {
        #pragma unroll
        for (int i=0;i<4;++i) As[sk+i][sr]=0.f;
      }
      const int k = kb + br;
      if (k < K){
        if (n0 + bc + 3 < N){
          float f[4]; load4(B + (long)k*ldb + n0 + bc, f);
          Bs[br][bc]=f[0]; Bs[br][bc+1]=f[1]; Bs[br][bc+2]=f[2]; Bs[br][bc+3]=f[3];
        } else {
          #pragma unroll
          for (int i=0;i<4;++i){ int n=n0+bc+i; Bs[br][bc+i] = (n<N)? B[(long)k*ldb+n] : 0.f; }
        }
      } else {
        #pragma unroll
        for (int i=0;i<4;++i) Bs[br][bc+i]=0.f;
      }
    }
    __syncthreads();
    #pragma unroll
    for (int k=0;k<16;++k){
      float a[4], b[4];
      *reinterpret_cast<float4*>(a) = *reinterpret_cast<const float4*>(&As[k][ty*4]);
      *reinterpret_cast<float4*>(b) = *reinterpret_cast<const float4*>(&Bs[k][tx*4]);
      #pragma unroll
      for (int i=0;i<4;++i)
        #pragma unroll
        for (int j=0;j<4;++j)
          acc[i][j] = fmaf(a[i], b[j], acc[i][j]);
    }
    __syncthreads();
  }
  #pragma unroll
  for (int i=0;i<4;++i){
    const int m = m0 + ty*4 + i;
    if (m >= M) continue;
    #pragma unroll
    for (int j=0;j<4;++j){
      const int n = n0 + tx*4 + j;
      if (n >= N) continue;
      float v = acc[i][j] * mult;
      const long idx = (long)m*ldc + n;
      if (ACC) v += C[idx];
      C[idx] = v;
    }
  }
}

// ---------------- hg chunk init: hg[bl,se,t*4+j] = relu(src[t,b,se]*Ru[se*4+j]) ----------------
__global__ void build_hg(const void* __restrict__ src, const float* __restrict__ Ru,
                         float* __restrict__ hg, const int* __restrict__ flag, int b0){
  const int t = blockIdx.x, bl = blockIdx.y, se = threadIdx.x;  // block 128
  const int f32 = *flag;
  const float s = rdIn(src, ((long)t*B_ + (b0+bl))*(2*SE_) + se, f32);
  const long o = ((long)bl*SE_ + se)*D_FEAT_ + t*4;
  #pragma unroll
  for (int j=0;j<4;++j){
    hg[o+j] = fmaxf(s*Ru[se*4+j], 0.f);
  }
}

// ---------------- xx chunk build: transpose hg + positional encoding ----------------
__global__ void build_xx(const float* __restrict__ hg, const float* __restrict__ times,
                         float* __restrict__ xx, int b0, int G){
  const int blk = blockIdx.x;          // t*G + bl
  const int t = blk / G, bl = blk % G, b = b0 + bl;
  const int tid = threadIdx.x;         // 256
  const float tm = times[(long)t*B_ + b];
  for (int c = tid; c < D_MODEL_; c += 256){
    float v;
    if (c < SE_*4){
      v = hg[((long)bl*SE_ + (c>>2))*D_FEAT_ + t*4 + (c&3)];
    } else {
      const int p = c - SE_*4;
      const int i = p & 7;
      const float ts = exp2f(8.0f * (float)i / 7.0f);   // 256^(i/7)
      const float st = tm / ts;
      v = (p < 8) ? sinf(st) : cosf(st);
    }
    xx[((long)t*B_ + b)*D_MODEL_ + c] = v;
  }
}

// ---------------- row softmax (key mask when lengths != null; rows = z*256+q, b = b0+z) ----------------
template<int COLS>
__global__ void softmax_k(float* __restrict__ S, const int* __restrict__ lengths, int b0){
  const long row = blockIdx.x;
  float* p = S + row * COLS;
  const int tid = threadIdx.x;
  float v = p[tid];
  if (lengths != nullptr){
    const int b = b0 + (int)(row >> 8);
    if (tid >= lengths[b]) v = -1e9f;
  }
  __shared__ float red[COLS];
  red[tid] = v; __syncthreads();
  for (int h = COLS/2; h>0; h>>=1){ if (tid<h) red[tid] = fmaxf(red[tid], red[tid+h]); __syncthreads(); }
  const float mx = red[0]; __syncthreads();
  const float e = expf(v - mx);
  red[tid] = e; __syncthreads();
  for (int h = COLS/2; h>0; h>>=1){ if (tid<h) red[tid] += red[tid+h]; __syncthreads(); }
  p[tid] = e / red[0];
}

// ---------------- elementwise a *= b ----------------
__global__ void mul_k(float* __restrict__ a, const float* __restrict__ b, long n){
  const long i = (long)blockIdx.x*256 + threadIdx.x;
  if (i < n) a[i] *= b[i];
}

// ---------------- LN body (row = 528) ----------------
__device__ __forceinline__ void ln_body(float* px, const float* pr,
                                        const float* g, const float* bb, int tid){
  const float x0 = px[tid]     + pr[tid];
  const float x1 = px[tid+256] + pr[tid+256];
  const float x2 = (tid < 16) ? (px[tid+512] + pr[tid+512]) : 0.f;
  __shared__ float rs[256];
  __shared__ float rq[256];
  rs[tid] = x0 + x1 + x2;
  rq[tid] = x0*x0 + x1*x1 + x2*x2;
  __syncthreads();
  for (int h = 128; h > 0; h >>= 1){
    if (tid < h){ rs[tid] += rs[tid+h]; rq[tid] += rq[tid+h]; }
    __syncthreads();
  }
  const float mean = rs[0] * (1.0f/528.0f);
  const float var  = rq[0] * (1.0f/528.0f) - mean*mean;
  const float inv = rsqrtf(var + 1e-5f);
  px[tid]     = (x0-mean)*inv*g[tid]     + bb[tid];
  px[tid+256] = (x1-mean)*inv*g[tid+256] + bb[tid+256];
  if (tid < 16) px[tid+512] = (x2-mean)*inv*g[tid+512] + bb[tid+512];
}

// res layout [z][t][528], xx rows t*B + (b0+z); blocks = 32*256
__global__ __launch_bounds__(256) void ln_res_attn(float* __restrict__ xx, const float* __restrict__ res,
                                                   const float* __restrict__ g, const float* __restrict__ bb,
                                                   int b0){
  const int z = blockIdx.x >> 8, t = blockIdx.x & 255;
  float* px = xx + ((long)t*B_ + b0 + z)*D_MODEL_;
  const float* pr = res + (long)blockIdx.x*D_MODEL_;
  ln_body(px, pr, g, bb, threadIdx.x);
}

// res rows 0..n, xx rows r0+blk
__global__ __launch_bounds__(256) void ln_res_rows(float* __restrict__ xx, const float* __restrict__ res,
                                                   const float* __restrict__ g, const float* __restrict__ bb,
                                                   int r0){
  float* px = xx + ((long)r0 + blockIdx.x)*D_MODEL_;
  const float* pr = res + (long)blockIdx.x*D_MODEL_;
  ln_body(px, pr, g, bb, threadIdx.x);
}

// ---------------- masked mean pool ----------------
__global__ void pool_k(const float* __restrict__ xx, const int* __restrict__ len,
                       float* __restrict__ pooled){
  const int b = blockIdx.y;
  const int c = blockIdx.x*256 + threadIdx.x;
  if (c >= D_MODEL_) return;
  const int L = len[b];
  float s = 0.f;
  for (int t = 0; t < L; ++t) s += xx[((long)t*B_ + b)*D_MODEL_ + c];
  pooled[(long)b*D_FINAL_ + c] = s / (float)(L + 1);
}

// ---------------- logits (output dtype per flag) ----------------
__global__ void logits_k(const float* __restrict__ hid, const float* __restrict__ W2,
                         const float* __restrict__ b2, void* __restrict__ out,
                         const int* __restrict__ flag){
  const int z = blockIdx.x;            // b*2 + c
  const int b = z >> 1, c = z & 1;
  const int lane = threadIdx.x;        // 64
  float s = 0.f;
  for (int k = lane; k < D_FINAL_; k += 64)
    s += hid[(long)b*D_FINAL_ + k] * W2[(long)c*D_FINAL_ + k];
  #pragma unroll
  for (int o = 32; o > 0; o >>= 1) s += __shfl_down(s, o, 64);
  if (lane == 0){
    const float r = s + b2[c];
    if (*flag) ((float*)out)[z] = r;
    else       ((bf16*)out)[z] = __float2bfloat16(r);
  }
}

// =======================================================================
// Arena (KiB offsets, peak 166.3 MiB — all f32):
//  [0, 47139)       weights f32 (46.03 MiB)       flag @ 47500
//  [48000, 115584)  xx f32 (66 MiB)
//  SC = 115600      scratch (54.1 MiB):
//   stage1 (16-batch chunks): hgA 0, hgB 8192, q 16384, k 24576, S0 32768, S1 33792
//   stage2 attn (32-batch chunks): qh 0, kh 4224, vh 8448, att 12672, o 20864, proj 37760
//   stage2 ff: ff1 0, proj2 16896    stage3: pooled 0, hid 1024
// =======================================================================
extern "C" void kernel_launch(void* const* d_in, const int* in_sizes, int n_in,
                              void* d_out, int out_size, void* d_ws, size_t ws_size,
                              hipStream_t stream) {
  const int* lengths = (const int*)d_in[2];
  char* ws = (char*)d_ws;
  const size_t KB = 1024;

  float* xx = (float*)(ws + 48000*KB);
  int* flag = (int*)(ws + 47500*KB);
  char* SC  = ws + 115600*KB;

  // stage-1 chunk scratch
  float* hgA = (float*)(SC + 0*KB);
  float* hgB = (float*)(SC + 8192*KB);
  float* q_c = (float*)(SC + 16384*KB);
  float* k_c = (float*)(SC + 24576*KB);
  float* S0c = (float*)(SC + 32768*KB);
  float* S1c = (float*)(SC + 33792*KB);
  // stage-2 attn scratch
  float* qh = (float*)(SC + 0*KB);
  float* kh = (float*)(SC + 4224*KB);
  float* vh = (float*)(SC + 8448*KB);
  float* att = (float*)(SC + 12672*KB);
  float* o_c = (float*)(SC + 20864*KB);
  float* pj  = (float*)(SC + 37760*KB);
  // stage-2 ff / stage-3
  float* ff1 = (float*)(SC + 0*KB);
  float* pj2 = (float*)(SC + 16896*KB);
  float* pooled = (float*)(SC + 0*KB);
  float* hid    = (float*)(SC + 1024*KB);

  // ---- dtype detect + normalize weights to f32 arena ----
  detect_k<<<1,256,0,stream>>>(d_in[0], flag);
  static const struct { int idx; long n; } cts[] = {
    {1,32768},{3,8192},{4,512},{5,32768},{6,512},
    {7,2097152},{8,2097152},{9,2097152},{10,2048},{11,2048},{12,2048},
    {13,2097152},{14,2048},{15,1672704},{16,3168},{17,557568},{18,1056},
    {19,135168},{20,256},{21,135168},{22,1056},{23,1056},{24,1056},{25,1056},
    {26,1056},{27,1081600},{28,1040},{29,2080},{30,2}};
  const float* W[32];
  {
    float* wts = (float*)ws;
    long off = 0;
    for (int i = 0; i < (int)(sizeof(cts)/sizeof(cts[0])); ++i){
      cvt_f32<<<(int)((cts[i].n+255)/256),256,0,stream>>>(d_in[cts[i].idx], wts+off, cts[i].n, flag);
      W[cts[i].idx] = wts + off;
      off += cts[i].n;
    }
  }

  // ================= stage 1 + xx build, 16-batch chunks =================
  const int G1 = 16;
  for (int b0 = 0; b0 < B_; b0 += G1){
    build_hg<<<dim3(T_, G1), 128, 0, stream>>>(d_in[0], W[4], hgA, flag, b0);
    float* cur = hgA; float* nxt = hgB;
    for (int l = 0; l < 2; ++l){
      const float* Wq = W[7]  + (size_t)l*D_FEAT_*D_FEAT_;
      const float* Wk = W[8]  + (size_t)l*D_FEAT_*D_FEAT_;
      const float* Wv = W[9]  + (size_t)l*D_FEAT_*D_FEAT_;
      const float* Wsk= W[13] + (size_t)l*D_FEAT_*D_FEAT_;
      const float* bq = W[10] + (size_t)l*D_FEAT_;
      const float* bk = W[11] + (size_t)l*D_FEAT_;
      const float* bv = W[12] + (size_t)l*D_FEAT_;
      const float* bs = W[14] + (size_t)l*D_FEAT_;
      float* S = (l == 0) ? S0c : S1c;
      const int M1 = G1*SE_;                          // 2048
      gemm_nt<false,false><<<dim3(16,M1/64,1),256,0,stream>>>(
          cur, Wq, bq, q_c, M1,1024,1024, 1024,1024,1024, 0,0,0, 1.f);
      gemm_nt<false,false><<<dim3(16,M1/64,1),256,0,stream>>>(
          cur, Wk, bk, k_c, M1,1024,1024, 1024,1024,1024, 0,0,0, 1.f);
      gemm_nt<false,false><<<dim3(2,2,G1),256,0,stream>>>(
          q_c, k_c, nullptr, S, 128,128,1024, 1024,1024,128,
          (long)SE_*1024,(long)SE_*1024,(long)SE_*SE_, 0.03125f);
      softmax_k<128><<<G1*SE_,128,0,stream>>>(S, nullptr, 0);
      gemm_nt<false,false><<<dim3(16,M1/64,1),256,0,stream>>>(
          cur, Wsk, bs, nxt, M1,1024,1024, 1024,1024,1024, 0,0,0, 1.f);
      gemm_nt<false,false><<<dim3(16,M1/64,1),256,0,stream>>>(
          cur, Wv, bv, q_c, M1,1024,1024, 1024,1024,1024, 0,0,0, 1.f);
      if (l == 1) mul_k<<<(G1*SE_*SE_)/256,256,0,stream>>>(S1c, S0c, (long)G1*SE_*SE_);
      gemm_nn<true><<<dim3(16,2,G1),256,0,stream>>>(
          S, q_c, nxt, 128,1024,128, 128,1024,1024,
          (long)SE_*SE_,(long)SE_*1024,(long)SE_*1024, 1.f);
      float* t_ = cur; cur = nxt; nxt = t_;
    }
    build_xx<<<T_*G1,256,0,stream>>>(cur, W[1], xx, b0, G1);
  }

  // ================= stage 2: transformer =================
  const float iscl = 1.0f / sqrtf((float)HD_);
  const int G2 = 32;
  const long LXX = (long)B_*D_MODEL_;                  // 67584
  for (int l = 0; l < 2; ++l){
    const float* Wqkv = W[15] + (size_t)l*(3*D_MODEL_)*D_MODEL_;
    const float* bqkv = W[16] + (size_t)l*(3*D_MODEL_);
    const float* Wo   = W[17] + (size_t)l*D_MODEL_*D_MODEL_;
    const float* bo   = W[18] + (size_t)l*D_MODEL_;
    const float* W1   = W[19] + (size_t)l*D_FF_*D_MODEL_;
    const float* b1   = W[20] + (size_t)l*D_FF_;
    const float* W2   = W[21] + (size_t)l*D_MODEL_*D_FF_;
    const float* b2   = W[22] + (size_t)l*D_MODEL_;
    const float* g1   = W[23] + (size_t)l*D_MODEL_;
    const float* bb1  = W[24] + (size_t)l*D_MODEL_;
    const float* g2   = W[25] + (size_t)l*D_MODEL_;
    const float* bb2  = W[26] + (size_t)l*D_MODEL_;

    for (int b0 = 0; b0 < B_; b0 += G2){
      for (int h = 0; h < NH_; ++h){
        // q/k/v chunk: layout [z][t][132]; A rows via lda over t, batch via sA over b
        gemm_nt<false,false><<<dim3(3,4,G2),256,0,stream>>>(
            xx + (long)b0*D_MODEL_, Wqkv + (size_t)(h*HD_)*D_MODEL_, bqkv + h*HD_, qh,
            256,HD_,D_MODEL_, LXX,D_MODEL_,HD_, D_MODEL_,0,(long)256*HD_, 1.f);
        gemm_nt<false,false><<<dim3(3,4,G2),256,0,stream>>>(
            xx + (long)b0*D_MODEL_, Wqkv + (size_t)(D_MODEL_+h*HD_)*D_MODEL_, bqkv + D_MODEL_+h*HD_, kh,
            256,HD_,D_MODEL_, LXX,D_MODEL_,HD_, D_MODEL_,0,(long)256*HD_, 1.f);
        gemm_nt<false,false><<<dim3(3,4,G2),256,0,stream>>>(
            xx + (long)b0*D_MODEL_, Wqkv + (size_t)(2*D_MODEL_+h*HD_)*D_MODEL_, bqkv + 2*D_MODEL_+h*HD_, vh,
            256,HD_,D_MODEL_, LXX,D_MODEL_,HD_, D_MODEL_,0,(long)256*HD_, 1.f);
        gemm_nt<false,false><<<dim3(4,4,G2),256,0,stream>>>(
            qh, kh, nullptr, att, 256,256,HD_, HD_,HD_,256,
            (long)256*HD_,(long)256*HD_,65536, iscl);
        softmax_k<256><<<G2*256,256,0,stream>>>(att, lengths, b0);
        gemm_nn<false><<<dim3(3,4,G2),256,0,stream>>>(
            att, vh, o_c + h*HD_, 256,HD_,256, 256,HD_,D_MODEL_,
            65536,(long)256*HD_,(long)256*D_MODEL_, 1.f);
      }
      gemm_nt<false,false><<<dim3(9,4,G2),256,0,stream>>>(
          o_c, Wo, bo, pj, 256,D_MODEL_,D_MODEL_, D_MODEL_,D_MODEL_,D_MODEL_,
          (long)256*D_MODEL_,0,(long)256*D_MODEL_, 1.f);
      ln_res_attn<<<G2*256,256,0,stream>>>(xx, pj, g1, bb1, b0);
    }

    gemm_nt<true,false><<<dim3(2,512,1),256,0,stream>>>(
        xx, W1, b1, ff1, 32768,D_FF_,D_MODEL_, D_MODEL_,D_MODEL_,D_FF_, 0,0,0, 1.f);
    for (int r0 = 0; r0 < 32768; r0 += 8192){
      gemm_nt<false,false><<<dim3(9,128,1),256,0,stream>>>(
          ff1 + (long)r0*D_FF_, W2, b2, pj2, 8192,D_MODEL_,D_FF_, D_FF_,D_FF_,D_MODEL_, 0,0,0, 1.f);
      ln_res_rows<<<8192,256,0,stream>>>(xx, pj2, g2, bb2, r0);
    }
  }

  // ================= stage 3: pool + MLP head =================
  pool_k<<<dim3(3,B_),256,0,stream>>>(xx, lengths, pooled);
  gemm_nt<false,false><<<dim3(8,2,1),256,0,stream>>>(
      W[3], W[5], W[6], pooled + D_MODEL_, 128,512,64, 64,64,D_FINAL_, 0,0,0, 1.f);
  gemm_nt<true,false><<<dim3(17,2,1),256,0,stream>>>(
      pooled, W[27], W[28], hid, 128,D_FINAL_,D_FINAL_, D_FINAL_,D_FINAL_,D_FINAL_, 0,0,0, 1.f);
  logits_k<<<B_*2,64,0,stream>>>(hid, W[29], W[30], d_out, flag);
}

// Round 5
// 12767.230 us; speedup vs baseline: 1.0805x; 1.0805x over previous
//
#include <hip/hip_runtime.h>
#include <hip/hip_bf16.h>
#include <math.h>

#define SE_    128
#define T_     256
#define B_     128
#define NH_    4
#define HD_    132
#define D_FEAT_ 1024
#define D_MODEL_ 528
#define D_FINAL_ 1040
#define D_FF_  128

typedef __hip_bfloat16 bf16;
typedef __attribute__((ext_vector_type(8))) short bf16x8v;
typedef __attribute__((ext_vector_type(4))) float f32x4;

__device__ __forceinline__ float toF(const float x){ return x; }
__device__ __forceinline__ float toF(const bf16 x){ return __bfloat162float(x); }
__device__ __forceinline__ void load4(const float* p, float f[4]){
  const float4 v = *reinterpret_cast<const float4*>(p);
  f[0]=v.x; f[1]=v.y; f[2]=v.z; f[3]=v.w;
}
__device__ __forceinline__ float rdIn(const void* p, long i, int f32){
  return f32 ? ((const float*)p)[i] : toF(((const bf16*)p)[i]);
}
__device__ __forceinline__ void split1(const float x, short& h, short& l){
  const bf16 hb = __float2bfloat16(x);
  const float r = x - __bfloat162float(hb);
  const bf16 lb = __float2bfloat16(r);
  h = __builtin_bit_cast(short, hb);
  l = __builtin_bit_cast(short, lb);
}

// ---------------- dtype detect: 1 = f32 inputs, 0 = bf16 ----------------
__global__ void detect_k(const void* __restrict__ src, int* __restrict__ flag){
  const unsigned int* p = (const unsigned int*)src;
  int bad = 0;
  for (int i = threadIdx.x; i < 4096; i += 256){
    const unsigned int lo = p[i] & 0xFFFFu;
    const unsigned int e = (lo >> 7) & 0xFFu;
    if (e >= 0xC0u) bad++;
  }
  __shared__ int red[256];
  red[threadIdx.x] = bad; __syncthreads();
  for (int h = 128; h > 0; h >>= 1){
    if (threadIdx.x < h) red[threadIdx.x] += red[threadIdx.x+h];
    __syncthreads();
  }
  if (threadIdx.x == 0) *flag = (red[0] > 64) ? 1 : 0;
}

__global__ void cvt_f32(const void* __restrict__ in, float* __restrict__ out, long n,
                        const int* __restrict__ flag){
  const long i = (long)blockIdx.x*256 + threadIdx.x;
  if (i >= n) return;
  out[i] = rdIn(in, i, *flag);
}

// =======================================================================
// bf16x3 emulated-f32 NT GEMM on MFMA:
//   C[m,n] (+)= mult * sum_k A[m,k]*B[n,k]  (+bias[n], relu; TRANSC: store C[n,m])
// f32 in/out; hi/lo split on the fly in LDS staging; 128x128x32 tile, 256 thr.
// Batch: z1 = blockIdx.z % nz1 (strides sA/sB/sC), z2 = blockIdx.z / nz1 (sA2/sB2/sC2).
// =======================================================================
template<bool RELU, bool ACC, bool TRANSC>
__global__ __launch_bounds__(256) void gemm_m(
    const float* __restrict__ Ag, const float* __restrict__ Bg,
    const float* __restrict__ bias, float* __restrict__ Cg,
    int M, int N, int K, long lda, long ldb, long ldc,
    int nz1, long sA, long sB, long sC, long sA2, long sB2, long sC2,
    float mult)
{
  __shared__ short As_h[128*40];
  __shared__ short As_l[128*40];
  __shared__ short Bs_h[128*40];
  __shared__ short Bs_l[128*40];

  const int tid = threadIdx.x;
  const int z1 = blockIdx.z % nz1, z2 = blockIdx.z / nz1;
  const float* A = Ag + (long)z1*sA + (long)z2*sA2;
  const float* B = Bg + (long)z1*sB + (long)z2*sB2;
  float*       C = Cg + (long)z1*sC + (long)z2*sC2;
  const int m0 = blockIdx.y * 128, n0 = blockIdx.x * 128;

  const int srow = tid >> 1;           // 0..127
  const int sc0  = (tid & 1) * 16;     // 0/16

  const int lane = tid & 63;
  const int wv = tid >> 6;             // wave 0..3
  const int wm = (wv >> 1) * 64;
  const int wn = (wv & 1) * 64;
  const int fr = lane & 15;
  const int kq = (lane >> 4) * 8;

  f32x4 acc[4][4] = {};

  for (int kb = 0; kb < K; kb += 32){
    // ---- stage A rows ----
    {
      const int gm = m0 + srow;
      const bool mv = (gm < M);
      #pragma unroll
      for (int q = 0; q < 4; ++q){
        const int col = sc0 + q*4;
        float f[4];
        if (mv && (kb + col + 3 < K)){
          load4(A + (long)gm*lda + kb + col, f);
        } else {
          #pragma unroll
          for (int e=0;e<4;++e){ const int k = kb+col+e; f[e] = (mv && k < K) ? A[(long)gm*lda+k] : 0.f; }
        }
        short4 h4, l4;
        split1(f[0], h4.x, l4.x); split1(f[1], h4.y, l4.y);
        split1(f[2], h4.z, l4.z); split1(f[3], h4.w, l4.w);
        *reinterpret_cast<short4*>(&As_h[srow*40 + col]) = h4;
        *reinterpret_cast<short4*>(&As_l[srow*40 + col]) = l4;
      }
      const int gn = n0 + srow;
      const bool nv = (gn < N);
      #pragma unroll
      for (int q = 0; q < 4; ++q){
        const int col = sc0 + q*4;
        float f[4];
        if (nv && (kb + col + 3 < K)){
          load4(B + (long)gn*ldb + kb + col, f);
        } else {
          #pragma unroll
          for (int e=0;e<4;++e){ const int k = kb+col+e; f[e] = (nv && k < K) ? B[(long)gn*ldb+k] : 0.f; }
        }
        short4 h4, l4;
        split1(f[0], h4.x, l4.x); split1(f[1], h4.y, l4.y);
        split1(f[2], h4.z, l4.z); split1(f[3], h4.w, l4.w);
        *reinterpret_cast<short4*>(&Bs_h[srow*40 + col]) = h4;
        *reinterpret_cast<short4*>(&Bs_l[srow*40 + col]) = l4;
      }
    }
    __syncthreads();

    // ---- fragments + MFMA ----
    bf16x8v ah[4], al[4], bh[4], bl[4];
    #pragma unroll
    for (int i=0;i<4;++i){
      ah[i] = *reinterpret_cast<const bf16x8v*>(&As_h[(wm + i*16 + fr)*40 + kq]);
      al[i] = *reinterpret_cast<const bf16x8v*>(&As_l[(wm + i*16 + fr)*40 + kq]);
      bh[i] = *reinterpret_cast<const bf16x8v*>(&Bs_h[(wn + i*16 + fr)*40 + kq]);
      bl[i] = *reinterpret_cast<const bf16x8v*>(&Bs_l[(wn + i*16 + fr)*40 + kq]);
    }
    #pragma unroll
    for (int i=0;i<4;++i)
      #pragma unroll
      for (int j=0;j<4;++j){
        acc[i][j] = __builtin_amdgcn_mfma_f32_16x16x32_bf16(ah[i], bh[j], acc[i][j], 0,0,0);
        acc[i][j] = __builtin_amdgcn_mfma_f32_16x16x32_bf16(ah[i], bl[j], acc[i][j], 0,0,0);
        acc[i][j] = __builtin_amdgcn_mfma_f32_16x16x32_bf16(al[i], bh[j], acc[i][j], 0,0,0);
      }
    __syncthreads();
  }

  // ---- epilogue: C/D layout col=lane&15, row=(lane>>4)*4+r ----
  const int cr = (lane >> 4) * 4;
  const int cc = lane & 15;
  #pragma unroll
  for (int i=0;i<4;++i){
    #pragma unroll
    for (int j=0;j<4;++j){
      #pragma unroll
      for (int r=0;r<4;++r){
        const int gm = m0 + wm + i*16 + cr + r;
        const int gn = n0 + wn + j*16 + cc;
        if (gm < M && gn < N){
          float v = acc[i][j][r] * mult;
          if (bias) v += bias[gn];
          if (RELU) v = fmaxf(v, 0.f);
          const long idx = TRANSC ? ((long)gn*ldc + gm) : ((long)gm*ldc + gn);
          if (ACC) v += C[idx];
          C[idx] = v;
        }
      }
    }
  }
}

// ---------------- hg chunk init ----------------
__global__ void build_hg(const void* __restrict__ src, const float* __restrict__ Ru,
                         float* __restrict__ hg, const int* __restrict__ flag, int b0){
  const int t = blockIdx.x, bl = blockIdx.y, se = threadIdx.x;  // block 128
  const int f32 = *flag;
  const float s = rdIn(src, ((long)t*B_ + (b0+bl))*(2*SE_) + se, f32);
  const long o = ((long)bl*SE_ + se)*D_FEAT_ + t*4;
  #pragma unroll
  for (int j=0;j<4;++j) hg[o+j] = fmaxf(s*Ru[se*4+j], 0.f);
}

// ---------------- xx chunk build ----------------
__global__ void build_xx(const float* __restrict__ hg, const float* __restrict__ times,
                         float* __restrict__ xx, int b0, int G){
  const int blk = blockIdx.x;          // t*G + bl
  const int t = blk / G, bl = blk % G, b = b0 + bl;
  const int tid = threadIdx.x;
  const float tm = times[(long)t*B_ + b];
  for (int c = tid; c < D_MODEL_; c += 256){
    float v;
    if (c < SE_*4){
      v = hg[((long)bl*SE_ + (c>>2))*D_FEAT_ + t*4 + (c&3)];
    } else {
      const int p = c - SE_*4;
      const int i = p & 7;
      const float ts = exp2f(8.0f * (float)i / 7.0f);
      const float st = tm / ts;
      v = (p < 8) ? sinf(st) : cosf(st);
    }
    xx[((long)t*B_ + b)*D_MODEL_ + c] = v;
  }
}

// ---------------- row softmax; mask key>=len[b], b = b0 + (row>>bshift) ----------------
template<int COLS>
__global__ void softmax_k(float* __restrict__ S, const int* __restrict__ lengths,
                          int b0, int bshift){
  const long row = blockIdx.x;
  float* p = S + row * COLS;
  const int tid = threadIdx.x;
  float v = p[tid];
  if (lengths != nullptr){
    const int b = b0 + (int)(row >> bshift);
    if (tid >= lengths[b]) v = -1e9f;
  }
  __shared__ float red[COLS];
  red[tid] = v; __syncthreads();
  for (int h = COLS/2; h>0; h>>=1){ if (tid<h) red[tid] = fmaxf(red[tid], red[tid+h]); __syncthreads(); }
  const float mx = red[0]; __syncthreads();
  const float e = expf(v - mx);
  red[tid] = e; __syncthreads();
  for (int h = COLS/2; h>0; h>>=1){ if (tid<h) red[tid] += red[tid+h]; __syncthreads(); }
  p[tid] = e / red[0];
}

__global__ void mul_k(float* __restrict__ a, const float* __restrict__ b, long n){
  const long i = (long)blockIdx.x*256 + threadIdx.x;
  if (i < n) a[i] *= b[i];
}

// ---------------- LN body (row = 528) ----------------
__device__ __forceinline__ void ln_body(float* px, const float* pr,
                                        const float* g, const float* bb, int tid){
  const float x0 = px[tid]     + pr[tid];
  const float x1 = px[tid+256] + pr[tid+256];
  const float x2 = (tid < 16) ? (px[tid+512] + pr[tid+512]) : 0.f;
  __shared__ float rs[256];
  __shared__ float rq[256];
  rs[tid] = x0 + x1 + x2;
  rq[tid] = x0*x0 + x1*x1 + x2*x2;
  __syncthreads();
  for (int h = 128; h > 0; h >>= 1){
    if (tid < h){ rs[tid] += rs[tid+h]; rq[tid] += rq[tid+h]; }
    __syncthreads();
  }
  const float mean = rs[0] * (1.0f/528.0f);
  const float var  = rq[0] * (1.0f/528.0f) - mean*mean;
  const float inv = rsqrtf(var + 1e-5f);
  px[tid]     = (x0-mean)*inv*g[tid]     + bb[tid];
  px[tid+256] = (x1-mean)*inv*g[tid+256] + bb[tid+256];
  if (tid < 16) px[tid+512] = (x2-mean)*inv*g[tid+512] + bb[tid+512];
}

__global__ __launch_bounds__(256) void ln_res_attn(float* __restrict__ xx, const float* __restrict__ res,
                                                   const float* __restrict__ g, const float* __restrict__ bb,
                                                   int b0){
  const int z = blockIdx.x >> 8, t = blockIdx.x & 255;
  float* px = xx + ((long)t*B_ + b0 + z)*D_MODEL_;
  const float* pr = res + (long)blockIdx.x*D_MODEL_;
  ln_body(px, pr, g, bb, threadIdx.x);
}

__global__ __launch_bounds__(256) void ln_res_rows(float* __restrict__ xx, const float* __restrict__ res,
                                                   const float* __restrict__ g, const float* __restrict__ bb,
                                                   int r0){
  float* px = xx + ((long)r0 + blockIdx.x)*D_MODEL_;
  const float* pr = res + (long)blockIdx.x*D_MODEL_;
  ln_body(px, pr, g, bb, threadIdx.x);
}

__global__ void pool_k(const float* __restrict__ xx, const int* __restrict__ len,
                       float* __restrict__ pooled){
  const int b = blockIdx.y;
  const int c = blockIdx.x*256 + threadIdx.x;
  if (c >= D_MODEL_) return;
  const int L = len[b];
  float s = 0.f;
  for (int t = 0; t < L; ++t) s += xx[((long)t*B_ + b)*D_MODEL_ + c];
  pooled[(long)b*D_FINAL_ + c] = s / (float)(L + 1);
}

__global__ void logits_k(const float* __restrict__ hid, const float* __restrict__ W2,
                         const float* __restrict__ b2, void* __restrict__ out,
                         const int* __restrict__ flag){
  const int z = blockIdx.x;            // b*2 + c
  const int b = z >> 1, c = z & 1;
  const int lane = threadIdx.x;        // 64
  float s = 0.f;
  for (int k = lane; k < D_FINAL_; k += 64)
    s += hid[(long)b*D_FINAL_ + k] * W2[(long)c*D_FINAL_ + k];
  #pragma unroll
  for (int o = 32; o > 0; o >>= 1) s += __shfl_down(s, o, 64);
  if (lane == 0){
    const float r = s + b2[c];
    if (*flag) ((float*)out)[z] = r;
    else       ((bf16*)out)[z] = __float2bfloat16(r);
  }
}

// =======================================================================
// Arena (KiB offsets, peak ~158 MiB — proven cap 167.3 MiB):
//  [0, 47139)  weights f32    flag @ 47500   [48000, 115584) xx f32
//  SC = 115600 scratch:
//   stage1: hgA 0, hgB 8192, q_c 16384, k_c/Vt 24576, S0 32768, S1 33792 (top 34816)
//   stage2: qh 0, kh 8448, vt 16896, att 25344, o_c 29440, pj 37888 (top 46336)
//           ff1 0 (16 MiB), pj2 16896 (16.5 MiB)
//   stage3: pooled 0, hid 1024
// =======================================================================
extern "C" void kernel_launch(void* const* d_in, const int* in_sizes, int n_in,
                              void* d_out, int out_size, void* d_ws, size_t ws_size,
                              hipStream_t stream) {
  const int* lengths = (const int*)d_in[2];
  char* ws = (char*)d_ws;
  const size_t KB = 1024;

  float* xx = (float*)(ws + 48000*KB);
  int* flag = (int*)(ws + 47500*KB);
  char* SC  = ws + 115600*KB;

  float* hgA = (float*)(SC + 0*KB);
  float* hgB = (float*)(SC + 8192*KB);
  float* q_c = (float*)(SC + 16384*KB);
  float* k_c = (float*)(SC + 24576*KB);   // also Vt [1024][2048]
  float* S0c = (float*)(SC + 32768*KB);
  float* S1c = (float*)(SC + 33792*KB);

  float* qh  = (float*)(SC + 0*KB);
  float* kh  = (float*)(SC + 8448*KB);
  float* vt  = (float*)(SC + 16896*KB);   // [z][528][256]
  float* att = (float*)(SC + 25344*KB);   // [z][h][256][256]
  float* o_c = (float*)(SC + 29440*KB);   // [z][256][528]
  float* pj  = (float*)(SC + 37888*KB);
  float* ff1 = (float*)(SC + 0*KB);
  float* pj2 = (float*)(SC + 16896*KB);
  float* pooled = (float*)(SC + 0*KB);
  float* hid    = (float*)(SC + 1024*KB);

  // ---- dtype detect + normalize weights ----
  detect_k<<<1,256,0,stream>>>(d_in[0], flag);
  static const struct { int idx; long n; } cts[] = {
    {1,32768},{3,8192},{4,512},{5,32768},{6,512},
    {7,2097152},{8,2097152},{9,2097152},{10,2048},{11,2048},{12,2048},
    {13,2097152},{14,2048},{15,1672704},{16,3168},{17,557568},{18,1056},
    {19,135168},{20,256},{21,135168},{22,1056},{23,1056},{24,1056},{25,1056},
    {26,1056},{27,1081600},{28,1040},{29,2080},{30,2}};
  const float* W[32];
  {
    float* wts = (float*)ws;
    long off = 0;
    for (int i = 0; i < (int)(sizeof(cts)/sizeof(cts[0])); ++i){
      cvt_f32<<<(int)((cts[i].n+255)/256),256,0,stream>>>(d_in[cts[i].idx], wts+off, cts[i].n, flag);
      W[cts[i].idx] = wts + off;
      off += cts[i].n;
    }
  }

  // ================= stage 1: propagation (16-batch chunks) =================
  const int G1 = 16;
  for (int b0 = 0; b0 < B_; b0 += G1){
    build_hg<<<dim3(T_, G1), 128, 0, stream>>>(d_in[0], W[4], hgA, flag, b0);
    float* cur = hgA; float* nxt = hgB;
    for (int l = 0; l < 2; ++l){
      const float* Wq = W[7]  + (size_t)l*D_FEAT_*D_FEAT_;
      const float* Wk = W[8]  + (size_t)l*D_FEAT_*D_FEAT_;
      const float* Wv = W[9]  + (size_t)l*D_FEAT_*D_FEAT_;
      const float* Wsk= W[13] + (size_t)l*D_FEAT_*D_FEAT_;
      const float* bq = W[10] + (size_t)l*D_FEAT_;
      const float* bk = W[11] + (size_t)l*D_FEAT_;
      const float* bv = W[12] + (size_t)l*D_FEAT_;
      const float* bs = W[14] + (size_t)l*D_FEAT_;
      float* S = (l == 0) ? S0c : S1c;
      gemm_m<false,false,false><<<dim3(8,16,1),256,0,stream>>>(
          cur, Wq, bq, q_c, 2048,1024,1024, 1024,1024,1024, 1,0,0,0,0,0,0, 1.f);
      gemm_m<false,false,false><<<dim3(8,16,1),256,0,stream>>>(
          cur, Wk, bk, k_c, 2048,1024,1024, 1024,1024,1024, 1,0,0,0,0,0,0, 1.f);
      gemm_m<false,false,false><<<dim3(1,1,G1),256,0,stream>>>(
          q_c, k_c, nullptr, S, 128,128,1024, 1024,1024,128,
          G1, 131072,131072,16384, 0,0,0, 0.03125f);
      softmax_k<128><<<G1*SE_,128,0,stream>>>(S, nullptr, 0, 0);
      gemm_m<false,false,false><<<dim3(8,16,1),256,0,stream>>>(
          cur, Wsk, bs, nxt, 2048,1024,1024, 1024,1024,1024, 1,0,0,0,0,0,0, 1.f);
      // V transposed -> Vt [1024][2048] (reuses k_c; k dead after scores)
      gemm_m<false,false,true><<<dim3(8,16,1),256,0,stream>>>(
          cur, Wv, bv, k_c, 2048,1024,1024, 1024,1024,2048, 1,0,0,0,0,0,0, 1.f);
      if (l == 1) mul_k<<<1024,256,0,stream>>>(S1c, S0c, (long)G1*SE_*SE_);
      // nxt += S @ V   (NT vs Vt: B[n=d][k=se] = Vt[d][z*128+se])
      gemm_m<false,true,false><<<dim3(8,1,G1),256,0,stream>>>(
          S, k_c, nullptr, nxt, 128,1024,128, 128,2048,1024,
          G1, 16384,128,131072, 0,0,0, 1.f);
      float* t_ = cur; cur = nxt; nxt = t_;
    }
    build_xx<<<T_*G1,256,0,stream>>>(cur, W[1], xx, b0, G1);
  }

  // ================= stage 2: transformer (16-batch chunks) =================
  const float iscl = 1.0f / sqrtf((float)HD_);
  const int G2 = 16;
  for (int l = 0; l < 2; ++l){
    const float* Wqkv = W[15] + (size_t)l*(3*D_MODEL_)*D_MODEL_;
    const float* bqkv = W[16] + (size_t)l*(3*D_MODEL_);
    const float* Wo   = W[17] + (size_t)l*D_MODEL_*D_MODEL_;
    const float* bo   = W[18] + (size_t)l*D_MODEL_;
    const float* W1   = W[19] + (size_t)l*D_FF_*D_MODEL_;
    const float* b1   = W[20] + (size_t)l*D_FF_;
    const float* W2   = W[21] + (size_t)l*D_MODEL_*D_FF_;
    const float* b2   = W[22] + (size_t)l*D_MODEL_;
    const float* g1   = W[23] + (size_t)l*D_MODEL_;
    const float* bb1  = W[24] + (size_t)l*D_MODEL_;
    const float* g2   = W[25] + (size_t)l*D_MODEL_;
    const float* bb2  = W[26] + (size_t)l*D_MODEL_;

    for (int b0 = 0; b0 < B_; b0 += G2){
      const float* xxc = xx + (long)b0*D_MODEL_;
      gemm_m<false,false,false><<<dim3(5,2,G2),256,0,stream>>>(
          xxc, Wqkv, bqkv, qh, 256,528,528, 67584,528,528,
          G2, 528,0,135168, 0,0,0, 1.f);
      gemm_m<false,false,false><<<dim3(5,2,G2),256,0,stream>>>(
          xxc, Wqkv + (size_t)528*528, bqkv + 528, kh, 256,528,528, 67584,528,528,
          G2, 528,0,135168, 0,0,0, 1.f);
      gemm_m<false,false,true><<<dim3(5,2,G2),256,0,stream>>>(
          xxc, Wqkv + (size_t)1056*528, bqkv + 1056, vt, 256,528,528, 67584,528,256,
          G2, 528,0,135168, 0,0,0, 1.f);
      // scores: z = h*G2 + zb decomposed as z1=zb (chunk), z2=h (head col/row offsets)
      gemm_m<false,false,false><<<dim3(2,2,G2*NH_),256,0,stream>>>(
          qh, kh, nullptr, att, 256,256,HD_, 528,528,256,
          G2, 135168,135168,262144, 132,132,65536, iscl);
      softmax_k<256><<<G2*NH_*256,256,0,stream>>>(att, lengths, b0, 10);
      // O = P @ V (NT vs vt): B[n=d][k=t'] = vt[z][h*132+d][t']
      gemm_m<false,false,false><<<dim3(2,2,G2*NH_),256,0,stream>>>(
          att, vt, nullptr, o_c, 256,HD_,256, 256,256,528,
          G2, 262144,135168,135168, 65536,33792,132, 1.f);
      gemm_m<false,false,false><<<dim3(5,2,G2),256,0,stream>>>(
          o_c, Wo, bo, pj, 256,528,528, 528,528,528,
          G2, 135168,0,135168, 0,0,0, 1.f);
      ln_res_attn<<<G2*256,256,0,stream>>>(xx, pj, g1, bb1, b0);
    }

    gemm_m<true,false,false><<<dim3(1,256,1),256,0,stream>>>(
        xx, W1, b1, ff1, 32768,128,528, 528,528,128, 1,0,0,0,0,0,0, 1.f);
    for (int r0 = 0; r0 < 32768; r0 += 8192){
      gemm_m<false,false,false><<<dim3(5,64,1),256,0,stream>>>(
          ff1 + (long)r0*D_FF_, W2, b2, pj2, 8192,528,128, 128,128,528, 1,0,0,0,0,0,0, 1.f);
      ln_res_rows<<<8192,256,0,stream>>>(xx, pj2, g2, bb2, r0);
    }
  }

  // ================= stage 3: pool + MLP head =================
  pool_k<<<dim3(3,B_),256,0,stream>>>(xx, lengths, pooled);
  gemm_m<false,false,false><<<dim3(4,1,1),256,0,stream>>>(
      W[3], W[5], W[6], pooled + D_MODEL_, 128,512,64, 64,64,D_FINAL_, 1,0,0,0,0,0,0, 1.f);
  gemm_m<true,false,false><<<dim3(9,1,1),256,0,stream>>>(
      pooled, W[27], W[28], hid, 128,D_FINAL_,D_FINAL_, D_FINAL_,D_FINAL_,D_FINAL_, 1,0,0,0,0,0,0, 1.f);
  logits_k<<<B_*2,64,0,stream>>>(hid, W[29], W[30], d_out, flag);
}

// Round 6
// 11840.632 us; speedup vs baseline: 1.1650x; 1.0783x over previous
//
#include <hip/hip_runtime.h>
#include <hip/hip_bf16.h>
#include <math.h>

#define SE_    128
#define T_     256
#define B_     128
#define NH_    4
#define HD_    132
#define D_MODEL_ 528
#define D_FINAL_ 1040
#define D_FF_  128

typedef __hip_bfloat16 bf16;
typedef __attribute__((ext_vector_type(8))) short bf16x8v;
typedef __attribute__((ext_vector_type(4))) float f32x4;

__device__ __forceinline__ float bfb(unsigned short u){
  union { float f; unsigned int i; } c; c.i = ((unsigned int)u) << 16; return c.f;
}
__device__ __forceinline__ unsigned short bfr(float x){
  unsigned u = __builtin_bit_cast(unsigned, x);
  unsigned r = (u + 0x7FFFu + ((u >> 16) & 1u)) >> 16;
  return (unsigned short)r;
}
__device__ __forceinline__ void split1(float x, short& h, short& l){
  const unsigned short hu = bfr(x);
  const unsigned short lu = bfr(x - bfb(hu));
  h = (short)hu; l = (short)lu;
}
// reconstruct pair value
__device__ __forceinline__ float prd(const short* p, long i, long lo){
  return bfb((unsigned short)p[i]) + bfb((unsigned short)p[i+lo]);
}
__device__ __forceinline__ float rdIn(const void* p, long i, int f32){
  return f32 ? ((const float*)p)[i] : __bfloat162float(((const bf16*)p)[i]);
}

// ---------------- dtype detect: 1 = f32 inputs, 0 = bf16 ----------------
__global__ void detect_k(const void* __restrict__ src, int* __restrict__ flag){
  const unsigned int* p = (const unsigned int*)src;
  int bad = 0;
  for (int i = threadIdx.x; i < 4096; i += 256){
    const unsigned int lo = p[i] & 0xFFFFu;
    const unsigned int e = (lo >> 7) & 0xFFu;
    if (e >= 0xC0u) bad++;
  }
  __shared__ int red[256];
  red[threadIdx.x] = bad; __syncthreads();
  for (int h = 128; h > 0; h >>= 1){
    if (threadIdx.x < h) red[threadIdx.x] += red[threadIdx.x+h];
    __syncthreads();
  }
  if (threadIdx.x == 0) *flag = (red[0] > 64) ? 1 : 0;
}

// ---------------- mega conversion: all weights -> hi/lo bf16 planes ----------------
#define MAXE 40
struct CvtTab {
  const void* src[MAXE];
  long srcOff[MAXE];
  long dstOff[MAXE];
  int n[MAXE];
  int bstart[MAXE];
  int cnt;
};
__global__ void cvt_all(CvtTab tb, short* __restrict__ wts, long loW, const int* __restrict__ flag){
  const int b = blockIdx.x;
  int e = 0;
  for (int i = 1; i < tb.cnt; ++i) if (tb.bstart[i] <= b) e = i;
  const long i = (long)(b - tb.bstart[e])*256 + threadIdx.x;
  if (i >= tb.n[e]) return;
  const float v = rdIn(tb.src[e], tb.srcOff[e] + i, *flag);
  short h, l; split1(v, h, l);
  wts[tb.dstOff[e] + i] = h;
  wts[tb.dstOff[e] + i + loW] = l;
}

// ---------------- staging: 16 cols (hi+lo) of one row half into LDS ----------------
template<bool SPL>
__device__ __forceinline__ void stage_tile(const void* P, long lo, long ld, int kb, int K,
                                           int g, bool valid, int srow, int sc0,
                                           short* Lh, short* Ll){
  #pragma unroll
  for (int q = 0; q < 4; ++q){
    const int k = kb + sc0 + q*4;
    int2 hv, lv;
    short* hs = (short*)&hv; short* ls = (short*)&lv;
    if (SPL){
      const float* Pf = (const float*)P;
      float f[4];
      if (valid && (k+3 < K)){
        const float4 t = *reinterpret_cast<const float4*>(Pf + (long)g*ld + k);
        f[0]=t.x; f[1]=t.y; f[2]=t.z; f[3]=t.w;
      } else {
        #pragma unroll
        for (int e2=0;e2<4;++e2) f[e2] = (valid && (k+e2) < K) ? Pf[(long)g*ld + k + e2] : 0.f;
      }
      #pragma unroll
      for (int e2=0;e2<4;++e2) split1(f[e2], hs[e2], ls[e2]);
    } else {
      const short* Ps = (const short*)P;
      if (valid && (k+3 < K)){
        hv = *reinterpret_cast<const int2*>(Ps + (long)g*ld + k);
        lv = *reinterpret_cast<const int2*>(Ps + lo + (long)g*ld + k);
      } else {
        #pragma unroll
        for (int e2=0;e2<4;++e2){
          const bool ok = valid && ((k+e2) < K);
          hs[e2] = ok ? Ps[(long)g*ld + k + e2] : (short)0;
          ls[e2] = ok ? Ps[lo + (long)g*ld + k + e2] : (short)0;
        }
      }
    }
    *reinterpret_cast<int2*>(&Lh[srow*40 + sc0 + q*4]) = hv;
    *reinterpret_cast<int2*>(&Ll[srow*40 + sc0 + q*4]) = lv;
  }
}

// =======================================================================
// bf16x3 emulated-f32 NT GEMM, pair-plane operands, routed pair epilogue.
// C[m,n] = sum_k A[m,k]*B[n,k] (+bias, relu). Routes split the N range.
// =======================================================================
struct Route { short* C; long ldc; long lo; long sC; long sC2; int nEnd; int fl; }; // fl: 1=trans 2=acc

template<bool SPLITA>
__global__ __launch_bounds__(256) void gemm_s(
    const void* __restrict__ Ag, long loA,
    const short* __restrict__ Bg, long loB,
    const short* __restrict__ bias, long loBias,
    int M, int N, int K, long lda, long ldb,
    int nz1, long sA, long sB, long sA2, long sB2,
    int relu, int nroute, Route r0, Route r1, Route r2, float mult)
{
  __shared__ short As_h[128*40], As_l[128*40], Bs_h[128*40], Bs_l[128*40];
  const int tid = threadIdx.x;
  const int z1 = blockIdx.z % nz1, z2 = blockIdx.z / nz1;
  const int m0 = blockIdx.y*128, n0 = blockIdx.x*128;
  const void* A;
  if (SPLITA) A = (const void*)((const float*)Ag + z1*sA + z2*sA2);
  else        A = (const void*)((const short*)Ag + z1*sA + z2*sA2);
  const short* B = Bg + z1*sB + z2*sB2;
  short* Cb0 = r0.C + z1*r0.sC + z2*r0.sC2;
  short* Cb1 = (nroute > 1) ? (r1.C + z1*r1.sC + z2*r1.sC2) : nullptr;
  short* Cb2 = (nroute > 2) ? (r2.C + z1*r2.sC + z2*r2.sC2) : nullptr;

  const int srow = tid >> 1, sc0 = (tid & 1)*16;
  const int lane = tid & 63, wv = tid >> 6;
  const int wm = (wv >> 1)*64, wn = (wv & 1)*64;
  const int fr = lane & 15, kq = (lane >> 4)*8;

  f32x4 acc[4][4] = {};
  for (int kb = 0; kb < K; kb += 32){
    stage_tile<SPLITA>(A, loA, lda, kb, K, m0+srow, (m0+srow) < M, srow, sc0, As_h, As_l);
    stage_tile<false >(B, loB, ldb, kb, K, n0+srow, (n0+srow) < N, srow, sc0, Bs_h, Bs_l);
    __syncthreads();
    bf16x8v ah[4], al[4], bh[4], bl[4];
    #pragma unroll
    for (int i=0;i<4;++i){
      ah[i] = *reinterpret_cast<const bf16x8v*>(&As_h[(wm + i*16 + fr)*40 + kq]);
      al[i] = *reinterpret_cast<const bf16x8v*>(&As_l[(wm + i*16 + fr)*40 + kq]);
      bh[i] = *reinterpret_cast<const bf16x8v*>(&Bs_h[(wn + i*16 + fr)*40 + kq]);
      bl[i] = *reinterpret_cast<const bf16x8v*>(&Bs_l[(wn + i*16 + fr)*40 + kq]);
    }
    #pragma unroll
    for (int i=0;i<4;++i)
      #pragma unroll
      for (int j=0;j<4;++j){
        acc[i][j] = __builtin_amdgcn_mfma_f32_16x16x32_bf16(ah[i], bh[j], acc[i][j], 0,0,0);
        acc[i][j] = __builtin_amdgcn_mfma_f32_16x16x32_bf16(ah[i], bl[j], acc[i][j], 0,0,0);
        acc[i][j] = __builtin_amdgcn_mfma_f32_16x16x32_bf16(al[i], bh[j], acc[i][j], 0,0,0);
      }
    __syncthreads();
  }

  const int cr = (lane >> 4)*4, cc = lane & 15;
  #pragma unroll
  for (int i=0;i<4;++i){
    #pragma unroll
    for (int j=0;j<4;++j){
      #pragma unroll
      for (int rr=0;rr<4;++rr){
        const int gm = m0 + wm + i*16 + cr + rr;
        const int gn = n0 + wn + j*16 + cc;
        if (gm < M && gn < N){
          float v = acc[i][j][rr] * mult;
          if (bias) v += prd(bias, gn, loBias);
          if (relu) v = fmaxf(v, 0.f);
          short* Cp; long ldc, lo; int fl, cn;
          if (nroute > 1 && gn >= r0.nEnd){
            if (nroute > 2 && gn >= r1.nEnd){ Cp=Cb2; ldc=r2.ldc; lo=r2.lo; fl=r2.fl; cn=gn-r1.nEnd; }
            else                            { Cp=Cb1; ldc=r1.ldc; lo=r1.lo; fl=r1.fl; cn=gn-r0.nEnd; }
          } else                            { Cp=Cb0; ldc=r0.ldc; lo=r0.lo; fl=r0.fl; cn=gn; }
          const long idx = (fl & 1) ? ((long)cn*ldc + gm) : ((long)gm*ldc + cn);
          if (fl & 2) v += prd(Cp, idx, lo);
          short h, l; split1(v, h, l);
          Cp[idx] = h; Cp[idx + lo] = l;
        }
      }
    }
  }
}

// =======================================================================
// scores GEMM + fused row softmax (+optional key-mask, +optional elementwise
// multiply by mulP after normalize). Block owns full rows (grid.x == 1).
// S is f32. N in {128,256}, rows per block = 128.
// =======================================================================
__global__ __launch_bounds__(256) void gemm_sm(
    const short* __restrict__ Ag, long loA, const short* __restrict__ Bg, long loB,
    int N, int K, long lda, long ldb,
    int nz1, long sA, long sB, long sA2, long sB2,
    float* __restrict__ Sg, long sS, long sS2, int ldS,
    float mult, const int* __restrict__ lengths, int b0,
    const float* __restrict__ mulP, long sMul)
{
  __shared__ short As_h[128*40], As_l[128*40], Bs_h[128*40], Bs_l[128*40];
  __shared__ float red[128][2];
  const int tid = threadIdx.x;
  const int z1 = blockIdx.z % nz1, z2 = blockIdx.z / nz1;
  const int m0 = blockIdx.y*128;
  const short* A = Ag + z1*sA + z2*sA2;
  const short* B = Bg + z1*sB + z2*sB2;
  float* S = Sg + z1*sS + z2*sS2;

  const int srow = tid >> 1, sc0 = (tid & 1)*16;
  const int lane = tid & 63, wv = tid >> 6;
  const int wm = (wv >> 1)*64, wn = (wv & 1)*64;
  const int fr = lane & 15, kq = (lane >> 4)*8;
  const int cr = (lane >> 4)*4, cc = lane & 15;

  for (int nh = 0; nh < N; nh += 128){
    f32x4 acc[4][4] = {};
    for (int kb = 0; kb < K; kb += 32){
      stage_tile<false>(A, loA, lda, kb, K, m0+srow, true, srow, sc0, As_h, As_l);
      stage_tile<false>(B, loB, ldb, kb, K, nh+srow, true, srow, sc0, Bs_h, Bs_l);
      __syncthreads();
      bf16x8v ah[4], al[4], bh[4], bl[4];
      #pragma unroll
      for (int i=0;i<4;++i){
        ah[i] = *reinterpret_cast<const bf16x8v*>(&As_h[(wm + i*16 + fr)*40 + kq]);
        al[i] = *reinterpret_cast<const bf16x8v*>(&As_l[(wm + i*16 + fr)*40 + kq]);
        bh[i] = *reinterpret_cast<const bf16x8v*>(&Bs_h[(wn + i*16 + fr)*40 + kq]);
        bl[i] = *reinterpret_cast<const bf16x8v*>(&Bs_l[(wn + i*16 + fr)*40 + kq]);
      }
      #pragma unroll
      for (int i=0;i<4;++i)
        #pragma unroll
        for (int j=0;j<4;++j){
          acc[i][j] = __builtin_amdgcn_mfma_f32_16x16x32_bf16(ah[i], bh[j], acc[i][j], 0,0,0);
          acc[i][j] = __builtin_amdgcn_mfma_f32_16x16x32_bf16(ah[i], bl[j], acc[i][j], 0,0,0);
          acc[i][j] = __builtin_amdgcn_mfma_f32_16x16x32_bf16(al[i], bh[j], acc[i][j], 0,0,0);
        }
      __syncthreads();
    }
    #pragma unroll
    for (int i=0;i<4;++i)
      #pragma unroll
      for (int j=0;j<4;++j)
        #pragma unroll
        for (int rr=0;rr<4;++rr){
          const int gm = m0 + wm + i*16 + cr + rr;
          const int gn = nh + wn + j*16 + cc;
          S[(long)gm*ldS + gn] = acc[i][j][rr] * mult;
        }
  }
  __syncthreads();   // drains vmcnt: S fully written, block-visible

  // ---- row softmax over cols [0,N) ----
  const int r = tid >> 1, half = tid & 1;
  float* row = S + (long)(m0 + r)*ldS;
  const int nv = N >> 1, c0 = half*nv;
  int lim = N;
  if (lengths){ const int L = lengths[b0 + z1]; lim = (L < N) ? L : N; }
  float mx = -3.0e38f;
  for (int i=0;i<nv;++i){ const int c = c0+i; if (c < lim) mx = fmaxf(mx, row[c]); }
  red[r][half] = mx;
  __syncthreads();
  mx = fmaxf(red[r][0], red[r][1]);
  __syncthreads();
  float sm = 0.f;
  for (int i=0;i<nv;++i){
    const int c = c0+i;
    float e = 0.f;
    if (c < lim) e = __expf(row[c] - mx);
    row[c] = e; sm += e;
  }
  red[r][half] = sm;
  __syncthreads();
  sm = red[r][0] + red[r][1];
  const float inv = 1.f / sm;
  if (mulP){
    const float* mr = mulP + z1*sMul + (long)(m0 + r)*ldS;
    for (int i=0;i<nv;++i){ const int c = c0+i; row[c] = row[c]*inv*mr[c]; }
  } else {
    for (int i=0;i<nv;++i){ const int c = c0+i; row[c] *= inv; }
  }
}

// ---------------- hg chunk init (pair out) ----------------
__global__ void build_hg(const void* __restrict__ src, const short* __restrict__ Ru, long loW,
                         short* __restrict__ hg, long loH, const int* __restrict__ flag, int b0){
  const int t = blockIdx.x, bl = blockIdx.y, se = threadIdx.x;  // block 128
  const int f32 = *flag;
  const float s = rdIn(src, ((long)t*B_ + (b0+bl))*(2*SE_) + se, f32);
  const long o = ((long)bl*SE_ + se)*1024 + t*4;
  #pragma unroll
  for (int j=0;j<4;++j){
    const float v = fmaxf(s * prd(Ru, se*4+j, loW), 0.f);
    short h, l; split1(v, h, l);
    hg[o+j] = h; hg[o+j+loH] = l;
  }
}

// ---------------- xx chunk build (pair in/out) ----------------
__global__ void build_xx(const short* __restrict__ hg, long loH,
                         const short* __restrict__ times, long loW,
                         short* __restrict__ xx, long loX, int b0, int G){
  const int blk = blockIdx.x;          // t*G + bl
  const int t = blk / G, bl = blk % G, b = b0 + bl;
  const int tid = threadIdx.x;
  const float tm = prd(times, (long)t*B_ + b, loW);
  for (int c = tid; c < D_MODEL_; c += 256){
    float v;
    if (c < SE_*4){
      v = prd(hg, ((long)bl*SE_ + (c>>2))*1024 + t*4 + (c&3), loH);
    } else {
      const int p = c - SE_*4;
      const int i = p & 7;
      const float ts = exp2f(8.0f * (float)i / 7.0f);
      const float st = tm / ts;
      v = (p < 8) ? sinf(st) : cosf(st);
    }
    short h, l; split1(v, h, l);
    const long o = ((long)t*B_ + b)*D_MODEL_ + c;
    xx[o] = h; xx[o+loX] = l;
  }
}

// ---------------- LN body (row = 528, pairs) ----------------
__device__ __forceinline__ void ln_body_p(short* px, long loX, const short* pr, long loR,
                                          const short* g, const short* bb, long loW, int tid){
  const float x0 = prd(px,tid,loX)     + prd(pr,tid,loR);
  const float x1 = prd(px,tid+256,loX) + prd(pr,tid+256,loR);
  const float x2 = (tid < 16) ? (prd(px,tid+512,loX) + prd(pr,tid+512,loR)) : 0.f;
  __shared__ float rs[256], rq[256];
  rs[tid] = x0 + x1 + x2;
  rq[tid] = x0*x0 + x1*x1 + x2*x2;
  __syncthreads();
  for (int h = 128; h > 0; h >>= 1){
    if (tid < h){ rs[tid] += rs[tid+h]; rq[tid] += rq[tid+h]; }
    __syncthreads();
  }
  const float mean = rs[0] * (1.0f/528.0f);
  const float var  = rq[0] * (1.0f/528.0f) - mean*mean;
  const float inv = rsqrtf(var + 1e-5f);
  short h, l;
  split1((x0-mean)*inv*prd(g,tid,loW) + prd(bb,tid,loW), h, l);
  px[tid] = h; px[tid+loX] = l;
  split1((x1-mean)*inv*prd(g,tid+256,loW) + prd(bb,tid+256,loW), h, l);
  px[tid+256] = h; px[tid+256+loX] = l;
  if (tid < 16){
    split1((x2-mean)*inv*prd(g,tid+512,loW) + prd(bb,tid+512,loW), h, l);
    px[tid+512] = h; px[tid+512+loX] = l;
  }
}

__global__ __launch_bounds__(256) void ln_res_attn(short* __restrict__ xx, long loX,
    const short* __restrict__ res, long loR,
    const short* __restrict__ g, const short* __restrict__ bb, long loW, int b0){
  const int z = blockIdx.x >> 8, t = blockIdx.x & 255;
  short* px = xx + ((long)t*B_ + b0 + z)*D_MODEL_;
  const short* pr = res + (long)blockIdx.x*D_MODEL_;
  ln_body_p(px, loX, pr, loR, g, bb, loW, threadIdx.x);
}

__global__ __launch_bounds__(256) void ln_res_rows(short* __restrict__ xx, long loX,
    const short* __restrict__ res, long loR,
    const short* __restrict__ g, const short* __restrict__ bb, long loW, int r0){
  short* px = xx + ((long)r0 + blockIdx.x)*D_MODEL_;
  const short* pr = res + (long)blockIdx.x*D_MODEL_;
  ln_body_p(px, loX, pr, loR, g, bb, loW, threadIdx.x);
}

// ---------------- masked mean pool (pair in/out) ----------------
__global__ void pool_k(const short* __restrict__ xx, long loX, const int* __restrict__ len,
                       short* __restrict__ pooled, long loP){
  const int b = blockIdx.y;
  const int c = blockIdx.x*256 + threadIdx.x;
  if (c >= D_MODEL_) return;
  const int L = len[b];
  float s = 0.f;
  for (int t = 0; t < L; ++t) s += prd(xx, ((long)t*B_ + b)*D_MODEL_ + c, loX);
  short h, l; split1(s / (float)(L + 1), h, l);
  pooled[(long)b*D_FINAL_ + c] = h;
  pooled[(long)b*D_FINAL_ + c + loP] = l;
}

// ---------------- logits (pair in, out dtype per flag) ----------------
__global__ void logits_k(const short* __restrict__ hid, long loH,
                         const short* __restrict__ W2, const short* __restrict__ b2, long loW,
                         void* __restrict__ out, const int* __restrict__ flag){
  const int z = blockIdx.x;            // b*2 + c
  const int b = z >> 1, c = z & 1;
  const int lane = threadIdx.x;        // 64
  float s = 0.f;
  for (int k = lane; k < D_FINAL_; k += 64)
    s += prd(hid, (long)b*D_FINAL_ + k, loH) * prd(W2, (long)c*D_FINAL_ + k, loW);
  #pragma unroll
  for (int o = 32; o > 0; o >>= 1) s += __shfl_down(s, o, 64);
  if (lane == 0){
    const float r = s + prd(b2, c, loW);
    if (*flag) ((float*)out)[z] = r;
    else       ((bf16*)out)[z] = __float2bfloat16(r);
  }
}

// =======================================================================
// Arena (KiB offsets, peak ~155 MiB, proven cap 167.3 MiB):
//  [0, ~47136)  weights pair planes (hi | lo)      flag @ 47500
//  [48000, 115584)  xx pair (66 MiB)
//  SC = 115600 scratch:
//   stage1: hgA 0 (8M), hgB 8192, qk_c 16384 (16M), Vt 32768 (8M), S0 40960, S1 41984
//   stage2: qkb 0 (16.5M) [o_c@0, pj@8448 after qk dead], vt 16896 (8.25M), att 25344 (16M f32)
//           ff1 0 (16M), pj2 16896 (16.5M)
//   stage3: pooled 0, hid 1024
// =======================================================================
extern "C" void kernel_launch(void* const* d_in, const int* in_sizes, int n_in,
                              void* d_out, int out_size, void* d_ws, size_t ws_size,
                              hipStream_t stream) {
  const int* lengths = (const int*)d_in[2];
  char* ws = (char*)d_ws;
  const size_t KB = 1024;

  short* wtsH = (short*)ws;
  int* flag = (int*)(ws + 47500*KB);
  short* xxH = (short*)(ws + 48000*KB);
  const long loXX = 17301504;
  char* SC = ws + 115600*KB;

  // stage-1 scratch
  short* hgA = (short*)(SC + 0*KB);      const long loHG = 2097152;
  short* hgB = (short*)(SC + 8192*KB);
  short* qkc = (short*)(SC + 16384*KB);  const long loQK1 = 4194304;
  short* VtS = (short*)(SC + 32768*KB);  const long loVT1 = 2097152;
  float* S0c = (float*)(SC + 40960*KB);
  float* S1c = (float*)(SC + 41984*KB);
  // stage-2 scratch
  short* qkb = (short*)(SC + 0*KB);      const long loQK2 = 4325376;
  short* o_c = (short*)(SC + 0*KB);      const long loOC  = 2162688;
  short* pjb = (short*)(SC + 8448*KB);   const long loPJ  = 2162688;
  short* vtb = (short*)(SC + 16896*KB);  const long loVT2 = 2162688;
  float* att = (float*)(SC + 25344*KB);
  short* ff1 = (short*)(SC + 0*KB);      const long loFF  = 4194304;
  short* pj2 = (short*)(SC + 16896*KB);  const long loPJ2 = 4325376;
  short* pooled = (short*)(SC + 0*KB);   const long loPO  = 133120;
  short* hid    = (short*)(SC + 1024*KB);

  // ---- conversion table (host-side) ----
  CvtTab tb; long cur = 0; int nb = 0; int e = 0;
  auto add = [&](int idx, long so, long n)->long{
    tb.src[e] = d_in[idx]; tb.srcOff[e] = so; tb.dstOff[e] = cur;
    tb.n[e] = (int)n; tb.bstart[e] = nb;
    nb += (int)((n + 255)/256); cur += n; e++;
    return cur - n;
  };
  const long oT  = add(1,0,32768);
  const long oSt = add(3,0,8192);
  const long oRu = add(4,0,512);
  const long oSW = add(5,0,32768);
  const long oSb = add(6,0,512);
  long oQKSV[2], oBQ[2];
  for (int l = 0; l < 2; ++l){
    oQKSV[l] = add(7, (long)l*1048576, 1048576);   // q
    add(8,  (long)l*1048576, 1048576);             // k
    add(13, (long)l*1048576, 1048576);             // skip
    add(9,  (long)l*1048576, 1048576);             // v
  }
  for (int l = 0; l < 2; ++l){
    oBQ[l] = add(10, (long)l*1024, 1024);          // bq
    add(11, (long)l*1024, 1024);                   // bk
    add(14, (long)l*1024, 1024);                   // bskip
    add(12, (long)l*1024, 1024);                   // bv
  }
  const long oWqkv = add(15,0,1672704);
  const long obqkv = add(16,0,3168);
  const long oWo = add(17,0,557568);
  const long obo = add(18,0,1056);
  const long oW1 = add(19,0,135168);
  const long ob1 = add(20,0,256);
  const long oW2 = add(21,0,135168);
  const long ob2 = add(22,0,1056);
  const long og1 = add(23,0,1056);
  const long obb1 = add(24,0,1056);
  const long og2 = add(25,0,1056);
  const long obb2 = add(26,0,1056);
  const long oM1 = add(27,0,1081600);
  const long oM1b = add(28,0,1040);
  const long oM2 = add(29,0,2080);
  const long oM2b = add(30,0,2);
  tb.cnt = e;
  const long loW = (cur + 7) & ~7L;   // padded plane stride

  detect_k<<<1,256,0,stream>>>(d_in[0], flag);
  cvt_all<<<nb,256,0,stream>>>(tb, wtsH, loW, flag);

  const Route RZ{nullptr,0,0,0,0,0,0};

  // ================= stage 1: propagation (16-batch chunks) =================
  const int G1 = 16;
  for (int b0 = 0; b0 < B_; b0 += G1){
    build_hg<<<dim3(T_, G1), 128, 0, stream>>>(d_in[0], wtsH+oRu, loW, hgA, loHG, flag, b0);
    short* curb = hgA; short* nxtb = hgB;
    for (int l = 0; l < 2; ++l){
      float* S = (l == 0) ? S0c : S1c;
      // fused [q|k|skip|v] GEMM: M=2048, N=4096, K=1024
      {
        Route q{qkc, 2048, loQK1, 0, 0, 2048, 0};
        Route s{nxtb, 1024, loHG, 0, 0, 3072, 0};
        Route v{VtS, 2048, loVT1, 0, 0, 4096, 1};   // transposed
        gemm_s<false><<<dim3(32,16,1),256,0,stream>>>(
            curb, loHG, wtsH+oQKSV[l], loW, wtsH+oBQ[l], loW,
            2048, 4096, 1024, 1024, 1024,
            1, 0,0,0,0, 0, 3, q, s, v, 1.f);
      }
      // scores + softmax (+mul for l==1)
      gemm_sm<<<dim3(1,1,G1),256,0,stream>>>(
          qkc, loQK1, qkc+1024, loQK1,
          128, 1024, 2048, 2048,
          G1, 262144, 262144, 0, 0,
          S, 16384, 0, 128,
          0.03125f, nullptr, 0,
          (l == 1) ? S0c : nullptr, 16384);
      // nxt += S @ V
      {
        Route c{nxtb, 1024, loHG, 131072, 0, 1024, 2};  // acc
        gemm_s<true><<<dim3(8,1,G1),256,0,stream>>>(
            S, 0, VtS, loVT1, nullptr, 0,
            128, 1024, 128, 128, 2048,
            G1, 16384, 128, 0, 0, 0, 1, c, RZ, RZ, 1.f);
      }
      short* t_ = curb; curb = nxtb; nxtb = t_;
    }
    build_xx<<<T_*G1,256,0,stream>>>(curb, loHG, wtsH+oT, loW, xxH, loXX, b0, G1);
  }

  // ================= stage 2: transformer (16-batch chunks) =================
  const float iscl = 1.0f / sqrtf((float)HD_);
  const int G2 = 16;
  for (int l = 0; l < 2; ++l){
    const long wqkv = oWqkv + (long)l*836352;
    const long bqkv = obqkv + (long)l*1584;
    for (int b0 = 0; b0 < B_; b0 += G2){
      // fused [q|k|v] GEMM: M=256(t), N=1584, K=528; v transposed to vtb
      {
        Route qk{qkb, 1056, loQK2, 270336, 0, 1056, 0};
        Route v{vtb, 256, loVT2, 135168, 0, 1584, 1};
        gemm_s<false><<<dim3(13,2,G2),256,0,stream>>>(
            xxH + (long)b0*D_MODEL_, loXX, wtsH+wqkv, loW, wtsH+bqkv, loW,
            256, 1584, 528, (long)B_*D_MODEL_, 528,
            G2, 528, 0, 0, 0, 0, 2, qk, v, RZ, 1.f);
      }
      // att scores + masked softmax
      gemm_sm<<<dim3(1,2,G2*NH_),256,0,stream>>>(
          qkb, loQK2, qkb+528, loQK2,
          256, HD_, 1056, 1056,
          G2, 270336, 270336, 132, 132,
          att, 262144, 65536, 256,
          iscl, lengths, b0, nullptr, 0);
      // O = P @ V
      {
        Route c{o_c, 528, loOC, 135168, 132, HD_, 0};
        gemm_s<true><<<dim3(2,2,G2*NH_),256,0,stream>>>(
            att, 0, vtb, loVT2, nullptr, 0,
            256, HD_, 256, 256, 256,
            G2, 262144, 135168, 65536, 33792, 0, 1, c, RZ, RZ, 1.f);
      }
      // Wo projection
      {
        Route c{pjb, 528, loPJ, 135168, 0, 528, 0};
        gemm_s<false><<<dim3(5,2,G2),256,0,stream>>>(
            o_c, loOC, wtsH+oWo+(long)l*278784, loW, wtsH+obo+(long)l*528, loW,
            256, 528, 528, 528, 528,
            G2, 135168, 0, 0, 0, 0, 1, c, RZ, RZ, 1.f);
      }
      ln_res_attn<<<G2*256,256,0,stream>>>(xxH, loXX, pjb, loPJ,
          wtsH+og1+(long)l*528, wtsH+obb1+(long)l*528, loW, b0);
    }
    // FF
    {
      Route c{ff1, 128, loFF, 0, 0, 128, 0};
      gemm_s<false><<<dim3(1,256,1),256,0,stream>>>(
          xxH, loXX, wtsH+oW1+(long)l*67584, loW, wtsH+ob1+(long)l*128, loW,
          32768, 128, 528, 528, 528,
          1, 0,0,0,0, 1, 1, c, RZ, RZ, 1.f);
    }
    for (int r0 = 0; r0 < 32768; r0 += 8192){
      Route c{pj2, 528, loPJ2, 0, 0, 528, 0};
      gemm_s<false><<<dim3(5,64,1),256,0,stream>>>(
          ff1 + (long)r0*128, loFF, wtsH+oW2+(long)l*67584, loW, wtsH+ob2+(long)l*528, loW,
          8192, 528, 128, 128, 128,
          1, 0,0,0,0, 0, 1, c, RZ, RZ, 1.f);
      ln_res_rows<<<8192,256,0,stream>>>(xxH, loXX, pj2, loPJ2,
          wtsH+og2+(long)l*528, wtsH+obb2+(long)l*528, loW, r0);
    }
  }

  // ================= stage 3: pool + MLP head =================
  pool_k<<<dim3(3,B_),256,0,stream>>>(xxH, loXX, lengths, pooled, loPO);
  {
    Route c{pooled + D_MODEL_, 1040, loPO, 0, 0, 512, 0};
    gemm_s<false><<<dim3(4,1,1),256,0,stream>>>(
        wtsH+oSt, loW, wtsH+oSW, loW, wtsH+oSb, loW,
        128, 512, 64, 64, 64,
        1, 0,0,0,0, 0, 1, c, RZ, RZ, 1.f);
  }
  {
    Route c{hid, 1040, loPO, 0, 0, 1040, 0};
    gemm_s<false><<<dim3(9,1,1),256,0,stream>>>(
        pooled, loPO, wtsH+oM1, loW, wtsH+oM1b, loW,
        128, 1040, 1040, 1040, 1040,
        1, 0,0,0,0, 1, 1, c, RZ, RZ, 1.f);
  }
  logits_k<<<B_*2,64,0,stream>>>(hid, loPO, wtsH+oM2, wtsH+oM2b, loW, d_out, flag);
}

// Round 7
// 8306.826 us; speedup vs baseline: 1.6606x; 1.4254x over previous
//
#include <hip/hip_runtime.h>
#include <hip/hip_bf16.h>
#include <math.h>

#define SE_    128
#define T_     256
#define B_     128
#define NH_    4
#define HD_    132
#define D_MODEL_ 528
#define D_FINAL_ 1040
#define D_FF_  128

typedef __hip_bfloat16 bf16;
typedef __attribute__((ext_vector_type(8))) short bf16x8v;
typedef __attribute__((ext_vector_type(4))) float f32x4;

__device__ __forceinline__ float bfb(unsigned short u){
  union { float f; unsigned int i; } c; c.i = ((unsigned int)u) << 16; return c.f;
}
__device__ __forceinline__ unsigned short bfr(float x){
  unsigned u = __builtin_bit_cast(unsigned, x);
  unsigned r = (u + 0x7FFFu + ((u >> 16) & 1u)) >> 16;
  return (unsigned short)r;
}
__device__ __forceinline__ void split1(float x, short& h, short& l){
  const unsigned short hu = bfr(x);
  const unsigned short lu = bfr(x - bfb(hu));
  h = (short)hu; l = (short)lu;
}
__device__ __forceinline__ float prd(const short* p, long i, long lo){
  return bfb((unsigned short)p[i]) + bfb((unsigned short)p[i+lo]);
}
__device__ __forceinline__ float rdIn(const void* p, long i, int f32){
  return f32 ? ((const float*)p)[i] : __bfloat162float(((const bf16*)p)[i]);
}

// ---------------- dtype detect: 1 = f32 inputs, 0 = bf16 ----------------
__global__ void detect_k(const void* __restrict__ src, int* __restrict__ flag){
  const unsigned int* p = (const unsigned int*)src;
  int bad = 0;
  for (int i = threadIdx.x; i < 4096; i += 256){
    const unsigned int lo = p[i] & 0xFFFFu;
    const unsigned int e = (lo >> 7) & 0xFFu;
    if (e >= 0xC0u) bad++;
  }
  __shared__ int red[256];
  red[threadIdx.x] = bad; __syncthreads();
  for (int h = 128; h > 0; h >>= 1){
    if (threadIdx.x < h) red[threadIdx.x] += red[threadIdx.x+h];
    __syncthreads();
  }
  if (threadIdx.x == 0) *flag = (red[0] > 64) ? 1 : 0;
}

// ---------------- mega conversion: all weights -> hi/lo bf16 planes ----------------
#define MAXE 40
struct CvtTab {
  const void* src[MAXE];
  long srcOff[MAXE];
  long dstOff[MAXE];
  int n[MAXE];
  int bstart[MAXE];
  int cnt;
};
__global__ void cvt_all(CvtTab tb, short* __restrict__ wts, long loW, const int* __restrict__ flag){
  const int b = blockIdx.x;
  int e = 0;
  for (int i = 1; i < tb.cnt; ++i) if (tb.bstart[i] <= b) e = i;
  const long i = (long)(b - tb.bstart[e])*256 + threadIdx.x;
  if (i >= tb.n[e]) return;
  const float v = rdIn(tb.src[e], tb.srcOff[e] + i, *flag);
  short h, l; split1(v, h, l);
  wts[tb.dstOff[e] + i] = h;
  wts[tb.dstOff[e] + i + loW] = l;
}

// ---------------- K-tile register loads (prefetchable) ----------------
struct RegsP { int4 v[4]; };   // [0..1]=hi 16 shorts, [2..3]=lo

template<bool A16>
__device__ __forceinline__ void ld_pair(const short* __restrict__ P, long lo, long ld,
                                        int kb, int K, int g, bool valid, int sc0, RegsP& r){
  short* a = (short*)r.v;
  const int k0 = kb + sc0;
  const short* ph = P + (long)g*ld + k0;
  if (valid && (k0 + 16 <= K)){
    if (A16){
      r.v[0] = *(const int4*)(ph);
      r.v[1] = *(const int4*)(ph + 8);
      r.v[2] = *(const int4*)(ph + lo);
      r.v[3] = *(const int4*)(ph + lo + 8);
    } else {
      #pragma unroll
      for (int q=0;q<4;++q){
        *(int2*)(a + q*4)      = *(const int2*)(ph + q*4);
        *(int2*)(a + 16 + q*4) = *(const int2*)(ph + lo + q*4);
      }
    }
  } else {
    #pragma unroll
    for (int e2=0;e2<16;++e2){
      const bool ok = valid && (k0 + e2 < K);
      a[e2]    = ok ? ph[e2] : (short)0;
      a[16+e2] = ok ? ph[lo + e2] : (short)0;
    }
  }
}

__device__ __forceinline__ void ld_f32(const float* __restrict__ P, long ld, int kb, int K,
                                       int g, bool valid, int sc0, float* f){
  const int k0 = kb + sc0;
  const float* p = P + (long)g*ld + k0;
  if (valid && (k0 + 16 <= K)){
    #pragma unroll
    for (int q=0;q<4;++q) *(float4*)(f+q*4) = *(const float4*)(p + q*4);
  } else {
    #pragma unroll
    for (int e2=0;e2<16;++e2) f[e2] = (valid && (k0+e2) < K) ? p[e2] : 0.f;
  }
}

__device__ __forceinline__ void wr_pair(const RegsP& r, short* Lh, short* Ll, int srow, int sc0){
  *(int4*)(&Lh[srow*40 + sc0])     = r.v[0];
  *(int4*)(&Lh[srow*40 + sc0 + 8]) = r.v[1];
  *(int4*)(&Ll[srow*40 + sc0])     = r.v[2];
  *(int4*)(&Ll[srow*40 + sc0 + 8]) = r.v[3];
}
__device__ __forceinline__ void wr_split(const float* f, short* Lh, short* Ll, int srow, int sc0){
  short h[16], l[16];
  #pragma unroll
  for (int e2=0;e2<16;++e2) split1(f[e2], h[e2], l[e2]);
  *(int4*)(&Lh[srow*40+sc0])   = *(const int4*)(h);
  *(int4*)(&Lh[srow*40+sc0+8]) = *(const int4*)(h+8);
  *(int4*)(&Ll[srow*40+sc0])   = *(const int4*)(l);
  *(int4*)(&Ll[srow*40+sc0+8]) = *(const int4*)(l+8);
}

// =======================================================================
// bf16x3 emulated-f32 NT GEMM, pair-plane operands, routed pair epilogue.
// Register-prefetched K-tiles; int4 staging (A16 = all bases 16B-aligned).
// =======================================================================
struct Route { short* C; long ldc; long lo; long sC; long sC2; int nEnd; int fl; }; // fl: 1=trans 2=acc

template<bool SPLITA, bool A16>
__global__ __launch_bounds__(256) void gemm_s(
    const void* __restrict__ Ag, long loA,
    const short* __restrict__ Bg, long loB,
    const short* __restrict__ bias, long loBias,
    int M, int N, int K, long lda, long ldb,
    int nz1, long sA, long sB, long sA2, long sB2,
    int relu, int nroute, Route r0, Route r1, Route r2, float mult)
{
  __shared__ short As_h[128*40], As_l[128*40], Bs_h[128*40], Bs_l[128*40];
  const int tid = threadIdx.x;
  const int z1 = blockIdx.z % nz1, z2 = blockIdx.z / nz1;
  const int m0 = blockIdx.y*128, n0 = blockIdx.x*128;
  const void* A;
  if (SPLITA) A = (const void*)((const float*)Ag + z1*sA + z2*sA2);
  else        A = (const void*)((const short*)Ag + z1*sA + z2*sA2);
  const short* B = Bg + z1*sB + z2*sB2;
  short* Cb0 = r0.C + z1*r0.sC + z2*r0.sC2;
  short* Cb1 = (nroute > 1) ? (r1.C + z1*r1.sC + z2*r1.sC2) : nullptr;
  short* Cb2 = (nroute > 2) ? (r2.C + z1*r2.sC + z2*r2.sC2) : nullptr;

  const int srow = tid >> 1, sc0 = (tid & 1)*16;
  const int lane = tid & 63, wv = tid >> 6;
  const int wm = (wv >> 1)*64, wn = (wv & 1)*64;
  const int fr = lane & 15, kq = (lane >> 4)*8;

  const int gm_s = m0 + srow; const bool mval = gm_s < M;
  const int gn_s = n0 + srow; const bool nval = gn_s < N;

  RegsP rA, rB; float fA[16];
  if (SPLITA) ld_f32((const float*)A, lda, 0, K, gm_s, mval, sc0, fA);
  else        ld_pair<A16>((const short*)A, loA, lda, 0, K, gm_s, mval, sc0, rA);
  ld_pair<A16>(B, loB, ldb, 0, K, gn_s, nval, sc0, rB);

  f32x4 acc[4][4] = {};
  for (int kb = 0; kb < K; kb += 32){
    if (SPLITA) wr_split(fA, As_h, As_l, srow, sc0);
    else        wr_pair(rA, As_h, As_l, srow, sc0);
    wr_pair(rB, Bs_h, Bs_l, srow, sc0);
    __syncthreads();
    const int kn = kb + 32;
    if (kn < K){
      if (SPLITA) ld_f32((const float*)A, lda, kn, K, gm_s, mval, sc0, fA);
      else        ld_pair<A16>((const short*)A, loA, lda, kn, K, gm_s, mval, sc0, rA);
      ld_pair<A16>(B, loB, ldb, kn, K, gn_s, nval, sc0, rB);
    }
    bf16x8v ah[4], al[4], bh[4], bl[4];
    #pragma unroll
    for (int i=0;i<4;++i){
      ah[i] = *reinterpret_cast<const bf16x8v*>(&As_h[(wm + i*16 + fr)*40 + kq]);
      al[i] = *reinterpret_cast<const bf16x8v*>(&As_l[(wm + i*16 + fr)*40 + kq]);
      bh[i] = *reinterpret_cast<const bf16x8v*>(&Bs_h[(wn + i*16 + fr)*40 + kq]);
      bl[i] = *reinterpret_cast<const bf16x8v*>(&Bs_l[(wn + i*16 + fr)*40 + kq]);
    }
    #pragma unroll
    for (int i=0;i<4;++i)
      #pragma unroll
      for (int j=0;j<4;++j){
        acc[i][j] = __builtin_amdgcn_mfma_f32_16x16x32_bf16(ah[i], bh[j], acc[i][j], 0,0,0);
        acc[i][j] = __builtin_amdgcn_mfma_f32_16x16x32_bf16(ah[i], bl[j], acc[i][j], 0,0,0);
        acc[i][j] = __builtin_amdgcn_mfma_f32_16x16x32_bf16(al[i], bh[j], acc[i][j], 0,0,0);
      }
    __syncthreads();
  }

  const int cr = (lane >> 4)*4, cc = lane & 15;
  #pragma unroll
  for (int i=0;i<4;++i){
    #pragma unroll
    for (int j=0;j<4;++j){
      #pragma unroll
      for (int rr=0;rr<4;++rr){
        const int gm = m0 + wm + i*16 + cr + rr;
        const int gn = n0 + wn + j*16 + cc;
        if (gm < M && gn < N){
          float v = acc[i][j][rr] * mult;
          if (bias) v += prd(bias, gn, loBias);
          if (relu) v = fmaxf(v, 0.f);
          short* Cp; long ldc, lo; int fl, cn;
          if (nroute > 1 && gn >= r0.nEnd){
            if (nroute > 2 && gn >= r1.nEnd){ Cp=Cb2; ldc=r2.ldc; lo=r2.lo; fl=r2.fl; cn=gn-r1.nEnd; }
            else                            { Cp=Cb1; ldc=r1.ldc; lo=r1.lo; fl=r1.fl; cn=gn-r0.nEnd; }
          } else                            { Cp=Cb0; ldc=r0.ldc; lo=r0.lo; fl=r0.fl; cn=gn; }
          const long idx = (fl & 1) ? ((long)cn*ldc + gm) : ((long)gm*ldc + cn);
          if (fl & 2) v += prd(Cp, idx, lo);
          short h, l; split1(v, h, l);
          Cp[idx] = h; Cp[idx + lo] = l;
        }
      }
    }
  }
}

// =======================================================================
// scores GEMM + fused row softmax (+key-mask, +elementwise mul) — prefetched.
// =======================================================================
template<bool A16>
__global__ __launch_bounds__(256) void gemm_sm(
    const short* __restrict__ Ag, long loA, const short* __restrict__ Bg, long loB,
    int N, int K, long lda, long ldb,
    int nz1, long sA, long sB, long sA2, long sB2,
    float* __restrict__ Sg, long sS, long sS2, int ldS,
    float mult, const int* __restrict__ lengths, int b0,
    const float* __restrict__ mulP, long sMul)
{
  __shared__ short As_h[128*40], As_l[128*40], Bs_h[128*40], Bs_l[128*40];
  __shared__ float red[128][2];
  const int tid = threadIdx.x;
  const int z1 = blockIdx.z % nz1, z2 = blockIdx.z / nz1;
  const int m0 = blockIdx.y*128;
  const short* A = Ag + z1*sA + z2*sA2;
  const short* B = Bg + z1*sB + z2*sB2;
  float* S = Sg + z1*sS + z2*sS2;

  const int srow = tid >> 1, sc0 = (tid & 1)*16;
  const int lane = tid & 63, wv = tid >> 6;
  const int wm = (wv >> 1)*64, wn = (wv & 1)*64;
  const int fr = lane & 15, kq = (lane >> 4)*8;
  const int cr = (lane >> 4)*4, cc = lane & 15;

  for (int nh = 0; nh < N; nh += 128){
    RegsP rA, rB;
    ld_pair<A16>(A, loA, lda, 0, K, m0+srow, true, sc0, rA);
    ld_pair<A16>(B, loB, ldb, 0, K, nh+srow, true, sc0, rB);
    f32x4 acc[4][4] = {};
    for (int kb = 0; kb < K; kb += 32){
      wr_pair(rA, As_h, As_l, srow, sc0);
      wr_pair(rB, Bs_h, Bs_l, srow, sc0);
      __syncthreads();
      const int kn = kb + 32;
      if (kn < K){
        ld_pair<A16>(A, loA, lda, kn, K, m0+srow, true, sc0, rA);
        ld_pair<A16>(B, loB, ldb, kn, K, nh+srow, true, sc0, rB);
      }
      bf16x8v ah[4], al[4], bh[4], bl[4];
      #pragma unroll
      for (int i=0;i<4;++i){
        ah[i] = *reinterpret_cast<const bf16x8v*>(&As_h[(wm + i*16 + fr)*40 + kq]);
        al[i] = *reinterpret_cast<const bf16x8v*>(&As_l[(wm + i*16 + fr)*40 + kq]);
        bh[i] = *reinterpret_cast<const bf16x8v*>(&Bs_h[(wn + i*16 + fr)*40 + kq]);
        bl[i] = *reinterpret_cast<const bf16x8v*>(&Bs_l[(wn + i*16 + fr)*40 + kq]);
      }
      #pragma unroll
      for (int i=0;i<4;++i)
        #pragma unroll
        for (int j=0;j<4;++j){
          acc[i][j] = __builtin_amdgcn_mfma_f32_16x16x32_bf16(ah[i], bh[j], acc[i][j], 0,0,0);
          acc[i][j] = __builtin_amdgcn_mfma_f32_16x16x32_bf16(ah[i], bl[j], acc[i][j], 0,0,0);
          acc[i][j] = __builtin_amdgcn_mfma_f32_16x16x32_bf16(al[i], bh[j], acc[i][j], 0,0,0);
        }
      __syncthreads();
    }
    #pragma unroll
    for (int i=0;i<4;++i)
      #pragma unroll
      for (int j=0;j<4;++j)
        #pragma unroll
        for (int rr=0;rr<4;++rr){
          const int gm = m0 + wm + i*16 + cr + rr;
          const int gn = nh + wn + j*16 + cc;
          S[(long)gm*ldS + gn] = acc[i][j][rr] * mult;
        }
  }
  __syncthreads();

  // ---- row softmax over cols [0,N) ----
  const int r = tid >> 1, half = tid & 1;
  float* row = S + (long)(m0 + r)*ldS;
  const int nv = N >> 1, c0 = half*nv;
  int lim = N;
  if (lengths){ const int L = lengths[b0 + z1]; lim = (L < N) ? L : N; }
  float mx = -3.0e38f;
  for (int i=0;i<nv;++i){ const int c = c0+i; if (c < lim) mx = fmaxf(mx, row[c]); }
  red[r][half] = mx;
  __syncthreads();
  mx = fmaxf(red[r][0], red[r][1]);
  __syncthreads();
  float sm = 0.f;
  for (int i=0;i<nv;++i){
    const int c = c0+i;
    float e = 0.f;
    if (c < lim) e = __expf(row[c] - mx);
    row[c] = e; sm += e;
  }
  red[r][half] = sm;
  __syncthreads();
  sm = red[r][0] + red[r][1];
  const float inv = 1.f / sm;
  if (mulP){
    const float* mr = mulP + z1*sMul + (long)(m0 + r)*ldS;
    for (int i=0;i<nv;++i){ const int c = c0+i; row[c] = row[c]*inv*mr[c]; }
  } else {
    for (int i=0;i<nv;++i){ const int c = c0+i; row[c] *= inv; }
  }
}

// ---------------- hg chunk init (pair out) ----------------
__global__ void build_hg(const void* __restrict__ src, const short* __restrict__ Ru, long loW,
                         short* __restrict__ hg, long loH, const int* __restrict__ flag, int b0){
  const int t = blockIdx.x, bl = blockIdx.y, se = threadIdx.x;  // block 128
  const int f32 = *flag;
  const float s = rdIn(src, ((long)t*B_ + (b0+bl))*(2*SE_) + se, f32);
  const long o = ((long)bl*SE_ + se)*1024 + t*4;
  #pragma unroll
  for (int j=0;j<4;++j){
    const float v = fmaxf(s * prd(Ru, se*4+j, loW), 0.f);
    short h, l; split1(v, h, l);
    hg[o+j] = h; hg[o+j+loH] = l;
  }
}

// ---------------- xx chunk build (pair in/out) ----------------
__global__ void build_xx(const short* __restrict__ hg, long loH,
                         const short* __restrict__ times, long loW,
                         short* __restrict__ xx, long loX, int b0, int G){
  const int blk = blockIdx.x;          // t*G + bl
  const int t = blk / G, bl = blk % G, b = b0 + bl;
  const int tid = threadIdx.x;
  const float tm = prd(times, (long)t*B_ + b, loW);
  for (int c = tid; c < D_MODEL_; c += 256){
    float v;
    if (c < SE_*4){
      v = prd(hg, ((long)bl*SE_ + (c>>2))*1024 + t*4 + (c&3), loH);
    } else {
      const int p = c - SE_*4;
      const int i = p & 7;
      const float ts = exp2f(8.0f * (float)i / 7.0f);
      const float st = tm / ts;
      v = (p < 8) ? sinf(st) : cosf(st);
    }
    short h, l; split1(v, h, l);
    const long o = ((long)t*B_ + b)*D_MODEL_ + c;
    xx[o] = h; xx[o+loX] = l;
  }
}

// ---------------- LN body (row = 528, pairs) ----------------
__device__ __forceinline__ void ln_body_p(short* px, long loX, const short* pr, long loR,
                                          const short* g, const short* bb, long loW, int tid){
  const float x0 = prd(px,tid,loX)     + prd(pr,tid,loR);
  const float x1 = prd(px,tid+256,loX) + prd(pr,tid+256,loR);
  const float x2 = (tid < 16) ? (prd(px,tid+512,loX) + prd(pr,tid+512,loR)) : 0.f;
  __shared__ float rs[256], rq[256];
  rs[tid] = x0 + x1 + x2;
  rq[tid] = x0*x0 + x1*x1 + x2*x2;
  __syncthreads();
  for (int h = 128; h > 0; h >>= 1){
    if (tid < h){ rs[tid] += rs[tid+h]; rq[tid] += rq[tid+h]; }
    __syncthreads();
  }
  const float mean = rs[0] * (1.0f/528.0f);
  const float var  = rq[0] * (1.0f/528.0f) - mean*mean;
  const float inv = rsqrtf(var + 1e-5f);
  short h, l;
  split1((x0-mean)*inv*prd(g,tid,loW) + prd(bb,tid,loW), h, l);
  px[tid] = h; px[tid+loX] = l;
  split1((x1-mean)*inv*prd(g,tid+256,loW) + prd(bb,tid+256,loW), h, l);
  px[tid+256] = h; px[tid+256+loX] = l;
  if (tid < 16){
    split1((x2-mean)*inv*prd(g,tid+512,loW) + prd(bb,tid+512,loW), h, l);
    px[tid+512] = h; px[tid+512+loX] = l;
  }
}

__global__ __launch_bounds__(256) void ln_res_attn(short* __restrict__ xx, long loX,
    const short* __restrict__ res, long loR,
    const short* __restrict__ g, const short* __restrict__ bb, long loW, int b0){
  const int z = blockIdx.x >> 8, t = blockIdx.x & 255;
  short* px = xx + ((long)t*B_ + b0 + z)*D_MODEL_;
  const short* pr = res + (long)blockIdx.x*D_MODEL_;
  ln_body_p(px, loX, pr, loR, g, bb, loW, threadIdx.x);
}

__global__ __launch_bounds__(256) void ln_res_rows(short* __restrict__ xx, long loX,
    const short* __restrict__ res, long loR,
    const short* __restrict__ g, const short* __restrict__ bb, long loW, int r0){
  short* px = xx + ((long)r0 + blockIdx.x)*D_MODEL_;
  const short* pr = res + (long)blockIdx.x*D_MODEL_;
  ln_body_p(px, loX, pr, loR, g, bb, loW, threadIdx.x);
}

// ---------------- masked mean pool (pair in/out) ----------------
__global__ void pool_k(const short* __restrict__ xx, long loX, const int* __restrict__ len,
                       short* __restrict__ pooled, long loP){
  const int b = blockIdx.y;
  const int c = blockIdx.x*256 + threadIdx.x;
  if (c >= D_MODEL_) return;
  const int L = len[b];
  float s = 0.f;
  for (int t = 0; t < L; ++t) s += prd(xx, ((long)t*B_ + b)*D_MODEL_ + c, loX);
  short h, l; split1(s / (float)(L + 1), h, l);
  pooled[(long)b*D_FINAL_ + c] = h;
  pooled[(long)b*D_FINAL_ + c + loP] = l;
}

// ---------------- logits (pair in, out dtype per flag) ----------------
__global__ void logits_k(const short* __restrict__ hid, long loH,
                         const short* __restrict__ W2, const short* __restrict__ b2, long loW,
                         void* __restrict__ out, const int* __restrict__ flag){
  const int z = blockIdx.x;            // b*2 + c
  const int b = z >> 1, c = z & 1;
  const int lane = threadIdx.x;        // 64
  float s = 0.f;
  for (int k = lane; k < D_FINAL_; k += 64)
    s += prd(hid, (long)b*D_FINAL_ + k, loH) * prd(W2, (long)c*D_FINAL_ + k, loW);
  #pragma unroll
  for (int o = 32; o > 0; o >>= 1) s += __shfl_down(s, o, 64);
  if (lane == 0){
    const float r = s + prd(b2, c, loW);
    if (*flag) ((float*)out)[z] = r;
    else       ((bf16*)out)[z] = __float2bfloat16(r);
  }
}

// =======================================================================
// Arena identical to round 6 (peak ~155 MiB, proven cap 167.3 MiB).
// =======================================================================
extern "C" void kernel_launch(void* const* d_in, const int* in_sizes, int n_in,
                              void* d_out, int out_size, void* d_ws, size_t ws_size,
                              hipStream_t stream) {
  const int* lengths = (const int*)d_in[2];
  char* ws = (char*)d_ws;
  const size_t KB = 1024;

  short* wtsH = (short*)ws;
  int* flag = (int*)(ws + 47500*KB);
  short* xxH = (short*)(ws + 48000*KB);
  const long loXX = 17301504;
  char* SC = ws + 115600*KB;

  short* hgA = (short*)(SC + 0*KB);      const long loHG = 2097152;
  short* hgB = (short*)(SC + 8192*KB);
  short* qkc = (short*)(SC + 16384*KB);  const long loQK1 = 4194304;
  short* VtS = (short*)(SC + 32768*KB);  const long loVT1 = 2097152;
  float* S0c = (float*)(SC + 40960*KB);
  float* S1c = (float*)(SC + 41984*KB);
  short* qkb = (short*)(SC + 0*KB);      const long loQK2 = 4325376;
  short* o_c = (short*)(SC + 0*KB);      const long loOC  = 2162688;
  short* pjb = (short*)(SC + 8448*KB);   const long loPJ  = 2162688;
  short* vtb = (short*)(SC + 16896*KB);  const long loVT2 = 2162688;
  float* att = (float*)(SC + 25344*KB);
  short* ff1 = (short*)(SC + 0*KB);      const long loFF  = 4194304;
  short* pj2 = (short*)(SC + 16896*KB);  const long loPJ2 = 4325376;
  short* pooled = (short*)(SC + 0*KB);   const long loPO  = 133120;
  short* hid    = (short*)(SC + 1024*KB);

  CvtTab tb; long cur = 0; int nb = 0; int e = 0;
  auto add = [&](int idx, long so, long n)->long{
    tb.src[e] = d_in[idx]; tb.srcOff[e] = so; tb.dstOff[e] = cur;
    tb.n[e] = (int)n; tb.bstart[e] = nb;
    nb += (int)((n + 255)/256); cur += n; e++;
    return cur - n;
  };
  const long oT  = add(1,0,32768);
  const long oSt = add(3,0,8192);
  const long oRu = add(4,0,512);
  const long oSW = add(5,0,32768);
  const long oSb = add(6,0,512);
  long oQKSV[2], oBQ[2];
  for (int l = 0; l < 2; ++l){
    oQKSV[l] = add(7, (long)l*1048576, 1048576);
    add(8,  (long)l*1048576, 1048576);
    add(13, (long)l*1048576, 1048576);
    add(9,  (long)l*1048576, 1048576);
  }
  for (int l = 0; l < 2; ++l){
    oBQ[l] = add(10, (long)l*1024, 1024);
    add(11, (long)l*1024, 1024);
    add(14, (long)l*1024, 1024);
    add(12, (long)l*1024, 1024);
  }
  const long oWqkv = add(15,0,1672704);
  const long obqkv = add(16,0,3168);
  const long oWo = add(17,0,557568);
  const long obo = add(18,0,1056);
  const long oW1 = add(19,0,135168);
  const long ob1 = add(20,0,256);
  const long oW2 = add(21,0,135168);
  const long ob2 = add(22,0,1056);
  const long og1 = add(23,0,1056);
  const long obb1 = add(24,0,1056);
  const long og2 = add(25,0,1056);
  const long obb2 = add(26,0,1056);
  const long oM1 = add(27,0,1081600);
  const long oM1b = add(28,0,1040);
  const long oM2 = add(29,0,2080);
  const long oM2b = add(30,0,2);
  tb.cnt = e;
  const long loW = (cur + 7) & ~7L;

  detect_k<<<1,256,0,stream>>>(d_in[0], flag);
  cvt_all<<<nb,256,0,stream>>>(tb, wtsH, loW, flag);

  const Route RZ{nullptr,0,0,0,0,0,0};

  // ================= stage 1: propagation (16-batch chunks) =================
  const int G1 = 16;
  for (int b0 = 0; b0 < B_; b0 += G1){
    build_hg<<<dim3(T_, G1), 128, 0, stream>>>(d_in[0], wtsH+oRu, loW, hgA, loHG, flag, b0);
    short* curb = hgA; short* nxtb = hgB;
    for (int l = 0; l < 2; ++l){
      float* S = (l == 0) ? S0c : S1c;
      {
        Route q{qkc, 2048, loQK1, 0, 0, 2048, 0};
        Route s{nxtb, 1024, loHG, 0, 0, 3072, 0};
        Route v{VtS, 2048, loVT1, 0, 0, 4096, 1};
        gemm_s<false,true><<<dim3(32,16,1),256,0,stream>>>(
            curb, loHG, wtsH+oQKSV[l], loW, wtsH+oBQ[l], loW,
            2048, 4096, 1024, 1024, 1024,
            1, 0,0,0,0, 0, 3, q, s, v, 1.f);
      }
      gemm_sm<true><<<dim3(1,1,G1),256,0,stream>>>(
          qkc, loQK1, qkc+1024, loQK1,
          128, 1024, 2048, 2048,
          G1, 262144, 262144, 0, 0,
          S, 16384, 0, 128,
          0.03125f, nullptr, 0,
          (l == 1) ? S0c : nullptr, 16384);
      {
        Route c{nxtb, 1024, loHG, 131072, 0, 1024, 2};
        gemm_s<true,true><<<dim3(8,1,G1),256,0,stream>>>(
            S, 0, VtS, loVT1, nullptr, 0,
            128, 1024, 128, 128, 2048,
            G1, 16384, 128, 0, 0, 0, 1, c, RZ, RZ, 1.f);
      }
      short* t_ = curb; curb = nxtb; nxtb = t_;
    }
    build_xx<<<T_*G1,256,0,stream>>>(curb, loHG, wtsH+oT, loW, xxH, loXX, b0, G1);
  }

  // ================= stage 2: transformer (16-batch chunks) =================
  const float iscl = 1.0f / sqrtf((float)HD_);
  const int G2 = 16;
  for (int l = 0; l < 2; ++l){
    const long wqkv = oWqkv + (long)l*836352;
    const long bqkv = obqkv + (long)l*1584;
    for (int b0 = 0; b0 < B_; b0 += G2){
      {
        Route qk{qkb, 1056, loQK2, 270336, 0, 1056, 0};
        Route v{vtb, 256, loVT2, 135168, 0, 1584, 1};
        gemm_s<false,true><<<dim3(13,2,G2),256,0,stream>>>(
            xxH + (long)b0*D_MODEL_, loXX, wtsH+wqkv, loW, wtsH+bqkv, loW,
            256, 1584, 528, (long)B_*D_MODEL_, 528,
            G2, 528, 0, 0, 0, 0, 2, qk, v, RZ, 1.f);
      }
      gemm_sm<false><<<dim3(1,2,G2*NH_),256,0,stream>>>(
          qkb, loQK2, qkb+528, loQK2,
          256, HD_, 1056, 1056,
          G2, 270336, 270336, 132, 132,
          att, 262144, 65536, 256,
          iscl, lengths, b0, nullptr, 0);
      {
        Route c{o_c, 528, loOC, 135168, 132, HD_, 0};
        gemm_s<true,true><<<dim3(2,2,G2*NH_),256,0,stream>>>(
            att, 0, vtb, loVT2, nullptr, 0,
            256, HD_, 256, 256, 256,
            G2, 262144, 135168, 65536, 33792, 0, 1, c, RZ, RZ, 1.f);
      }
      {
        Route c{pjb, 528, loPJ, 135168, 0, 528, 0};
        gemm_s<false,true><<<dim3(5,2,G2),256,0,stream>>>(
            o_c, loOC, wtsH+oWo+(long)l*278784, loW, wtsH+obo+(long)l*528, loW,
            256, 528, 528, 528, 528,
            G2, 135168, 0, 0, 0, 0, 1, c, RZ, RZ, 1.f);
      }
      ln_res_attn<<<G2*256,256,0,stream>>>(xxH, loXX, pjb, loPJ,
          wtsH+og1+(long)l*528, wtsH+obb1+(long)l*528, loW, b0);
    }
    {
      Route c{ff1, 128, loFF, 0, 0, 128, 0};
      gemm_s<false,true><<<dim3(1,256,1),256,0,stream>>>(
          xxH, loXX, wtsH+oW1+(long)l*67584, loW, wtsH+ob1+(long)l*128, loW,
          32768, 128, 528, 528, 528,
          1, 0,0,0,0, 1, 1, c, RZ, RZ, 1.f);
    }
    for (int r0 = 0; r0 < 32768; r0 += 8192){
      Route c{pj2, 528, loPJ2, 0, 0, 528, 0};
      gemm_s<false,true><<<dim3(5,64,1),256,0,stream>>>(
          ff1 + (long)r0*128, loFF, wtsH+oW2+(long)l*67584, loW, wtsH+ob2+(long)l*528, loW,
          8192, 528, 128, 128, 128,
          1, 0,0,0,0, 0, 1, c, RZ, RZ, 1.f);
      ln_res_rows<<<8192,256,0,stream>>>(xxH, loXX, pj2, loPJ2,
          wtsH+og2+(long)l*528, wtsH+obb2+(long)l*528, loW, r0);
    }
  }

  // ================= stage 3: pool + MLP head =================
  pool_k<<<dim3(3,B_),256,0,stream>>>(xxH, loXX, lengths, pooled, loPO);
  {
    Route c{pooled + D_MODEL_, 1040, loPO, 0, 0, 512, 0};
    gemm_s<false,true><<<dim3(4,1,1),256,0,stream>>>(
        wtsH+oSt, loW, wtsH+oSW, loW, wtsH+oSb, loW,
        128, 512, 64, 64, 64,
        1, 0,0,0,0, 0, 1, c, RZ, RZ, 1.f);
  }
  {
    Route c{hid, 1040, loPO, 0, 0, 1040, 0};
    gemm_s<false,true><<<dim3(9,1,1),256,0,stream>>>(
        pooled, loPO, wtsH+oM1, loW, wtsH+oM1b, loW,
        128, 1040, 1040, 1040, 1040,
        1, 0,0,0,0, 1, 1, c, RZ, RZ, 1.f);
  }
  logits_k<<<B_*2,64,0,stream>>>(hid, loPO, wtsH+oM2, wtsH+oM2b, loW, d_out, flag);
}

// Round 8
// 7322.835 us; speedup vs baseline: 1.8838x; 1.1344x over previous
//
#include <hip/hip_runtime.h>
#include <hip/hip_bf16.h>
#include <math.h>

#define SE_    128
#define T_     256
#define B_     128
#define NH_    4
#define HD_    132
#define D_MODEL_ 528
#define D_FINAL_ 1040
#define D_FF_  128

typedef __hip_bfloat16 bf16;
typedef __attribute__((ext_vector_type(8))) short bf16x8v;
typedef __attribute__((ext_vector_type(4))) float f32x4;

__device__ __forceinline__ float bfb(unsigned short u){
  union { float f; unsigned int i; } c; c.i = ((unsigned int)u) << 16; return c.f;
}
__device__ __forceinline__ unsigned short bfr(float x){
  unsigned u = __builtin_bit_cast(unsigned, x);
  unsigned r = (u + 0x7FFFu + ((u >> 16) & 1u)) >> 16;
  return (unsigned short)r;
}
__device__ __forceinline__ void split1(float x, short& h, short& l){
  const unsigned short hu = bfr(x);
  const unsigned short lu = bfr(x - bfb(hu));
  h = (short)hu; l = (short)lu;
}
__device__ __forceinline__ float prd(const short* p, long i, long lo){
  return bfb((unsigned short)p[i]) + bfb((unsigned short)p[i+lo]);
}
__device__ __forceinline__ float rdIn(const void* p, long i, int f32){
  return f32 ? ((const float*)p)[i] : __bfloat162float(((const bf16*)p)[i]);
}

// ---------------- dtype detect: 1 = f32 inputs, 0 = bf16 ----------------
__global__ void detect_k(const void* __restrict__ src, int* __restrict__ flag){
  const unsigned int* p = (const unsigned int*)src;
  int bad = 0;
  for (int i = threadIdx.x; i < 4096; i += 256){
    const unsigned int lo = p[i] & 0xFFFFu;
    const unsigned int e = (lo >> 7) & 0xFFu;
    if (e >= 0xC0u) bad++;
  }
  __shared__ int red[256];
  red[threadIdx.x] = bad; __syncthreads();
  for (int h = 128; h > 0; h >>= 1){
    if (threadIdx.x < h) red[threadIdx.x] += red[threadIdx.x+h];
    __syncthreads();
  }
  if (threadIdx.x == 0) *flag = (red[0] > 64) ? 1 : 0;
}

// ---------------- mega conversion: all weights -> hi/lo bf16 planes ----------------
#define MAXE 40
struct CvtTab {
  const void* src[MAXE];
  long srcOff[MAXE];
  long dstOff[MAXE];
  int n[MAXE];
  int bstart[MAXE];
  int cnt;
};
__global__ void cvt_all(CvtTab tb, short* __restrict__ wts, long loW, const int* __restrict__ flag){
  const int b = blockIdx.x;
  int e = 0;
  for (int i = 1; i < tb.cnt; ++i) if (tb.bstart[i] <= b) e = i;
  const long i = (long)(b - tb.bstart[e])*256 + threadIdx.x;
  if (i >= tb.n[e]) return;
  const float v = rdIn(tb.src[e], tb.srcOff[e] + i, *flag);
  short h, l; split1(v, h, l);
  wts[tb.dstOff[e] + i] = h;
  wts[tb.dstOff[e] + i + loW] = l;
}

// ---------------- K-tile register loads (prefetchable) ----------------
struct RegsP { int4 v[4]; };   // [0..1]=hi 16 shorts, [2..3]=lo

template<bool A16>
__device__ __forceinline__ void ld_pair(const short* __restrict__ P, long lo, long ld,
                                        int kb, int K, int g, bool valid, int sc0, RegsP& r){
  short* a = (short*)r.v;
  const int k0 = kb + sc0;
  const short* ph = P + (long)g*ld + k0;
  if (valid && (k0 + 16 <= K)){
    if (A16){
      r.v[0] = *(const int4*)(ph);
      r.v[1] = *(const int4*)(ph + 8);
      r.v[2] = *(const int4*)(ph + lo);
      r.v[3] = *(const int4*)(ph + lo + 8);
    } else {
      #pragma unroll
      for (int q=0;q<4;++q){
        *(int2*)(a + q*4)      = *(const int2*)(ph + q*4);
        *(int2*)(a + 16 + q*4) = *(const int2*)(ph + lo + q*4);
      }
    }
  } else {
    #pragma unroll
    for (int e2=0;e2<16;++e2){
      const bool ok = valid && (k0 + e2 < K);
      a[e2]    = ok ? ph[e2] : (short)0;
      a[16+e2] = ok ? ph[lo + e2] : (short)0;
    }
  }
}

__device__ __forceinline__ void ld_f32(const float* __restrict__ P, long ld, int kb, int K,
                                       int g, bool valid, int sc0, float* f){
  const int k0 = kb + sc0;
  const float* p = P + (long)g*ld + k0;
  if (valid && (k0 + 16 <= K)){
    #pragma unroll
    for (int q=0;q<4;++q) *(float4*)(f+q*4) = *(const float4*)(p + q*4);
  } else {
    #pragma unroll
    for (int e2=0;e2<16;++e2) f[e2] = (valid && (k0+e2) < K) ? p[e2] : 0.f;
  }
}

__device__ __forceinline__ void wr_pair(const RegsP& r, short* Lh, short* Ll, int srow, int sc0){
  *(int4*)(&Lh[srow*40 + sc0])     = r.v[0];
  *(int4*)(&Lh[srow*40 + sc0 + 8]) = r.v[1];
  *(int4*)(&Ll[srow*40 + sc0])     = r.v[2];
  *(int4*)(&Ll[srow*40 + sc0 + 8]) = r.v[3];
}
__device__ __forceinline__ void wr_split(const float* f, short* Lh, short* Ll, int srow, int sc0){
  short h[16], l[16];
  #pragma unroll
  for (int e2=0;e2<16;++e2) split1(f[e2], h[e2], l[e2]);
  *(int4*)(&Lh[srow*40+sc0])   = *(const int4*)(h);
  *(int4*)(&Lh[srow*40+sc0+8]) = *(const int4*)(h+8);
  *(int4*)(&Ll[srow*40+sc0])   = *(const int4*)(l);
  *(int4*)(&Ll[srow*40+sc0+8]) = *(const int4*)(l+8);
}

// =======================================================================
// bf16x3 emulated-f32 NT GEMM, pair-plane operands, routed pair epilogue.
// =======================================================================
struct Route { short* C; long ldc; long lo; long sC; long sC2; int nEnd; int fl; }; // fl: 1=trans 2=acc

template<bool SPLITA, bool A16>
__global__ __launch_bounds__(256) void gemm_s(
    const void* __restrict__ Ag, long loA,
    const short* __restrict__ Bg, long loB,
    const short* __restrict__ bias, long loBias,
    int M, int N, int K, long lda, long ldb,
    int nz1, long sA, long sB, long sA2, long sB2,
    int relu, int nroute, Route r0, Route r1, Route r2, float mult)
{
  __shared__ short As_h[128*40], As_l[128*40], Bs_h[128*40], Bs_l[128*40];
  const int tid = threadIdx.x;
  const int z1 = blockIdx.z % nz1, z2 = blockIdx.z / nz1;
  const int m0 = blockIdx.y*128, n0 = blockIdx.x*128;
  const void* A;
  if (SPLITA) A = (const void*)((const float*)Ag + z1*sA + z2*sA2);
  else        A = (const void*)((const short*)Ag + z1*sA + z2*sA2);
  const short* B = Bg + z1*sB + z2*sB2;
  short* Cb0 = r0.C + z1*r0.sC + z2*r0.sC2;
  short* Cb1 = (nroute > 1) ? (r1.C + z1*r1.sC + z2*r1.sC2) : nullptr;
  short* Cb2 = (nroute > 2) ? (r2.C + z1*r2.sC + z2*r2.sC2) : nullptr;

  const int srow = tid >> 1, sc0 = (tid & 1)*16;
  const int lane = tid & 63, wv = tid >> 6;
  const int wm = (wv >> 1)*64, wn = (wv & 1)*64;
  const int fr = lane & 15, kq = (lane >> 4)*8;

  const int gm_s = m0 + srow; const bool mval = gm_s < M;
  const int gn_s = n0 + srow; const bool nval = gn_s < N;

  RegsP rA, rB; float fA[16];
  if (SPLITA) ld_f32((const float*)A, lda, 0, K, gm_s, mval, sc0, fA);
  else        ld_pair<A16>((const short*)A, loA, lda, 0, K, gm_s, mval, sc0, rA);
  ld_pair<A16>(B, loB, ldb, 0, K, gn_s, nval, sc0, rB);

  f32x4 acc[4][4] = {};
  for (int kb = 0; kb < K; kb += 32){
    if (SPLITA) wr_split(fA, As_h, As_l, srow, sc0);
    else        wr_pair(rA, As_h, As_l, srow, sc0);
    wr_pair(rB, Bs_h, Bs_l, srow, sc0);
    __syncthreads();
    const int kn = kb + 32;
    if (kn < K){
      if (SPLITA) ld_f32((const float*)A, lda, kn, K, gm_s, mval, sc0, fA);
      else        ld_pair<A16>((const short*)A, loA, lda, kn, K, gm_s, mval, sc0, rA);
      ld_pair<A16>(B, loB, ldb, kn, K, gn_s, nval, sc0, rB);
    }
    bf16x8v ah[4], al[4], bh[4], bl[4];
    #pragma unroll
    for (int i=0;i<4;++i){
      ah[i] = *reinterpret_cast<const bf16x8v*>(&As_h[(wm + i*16 + fr)*40 + kq]);
      al[i] = *reinterpret_cast<const bf16x8v*>(&As_l[(wm + i*16 + fr)*40 + kq]);
      bh[i] = *reinterpret_cast<const bf16x8v*>(&Bs_h[(wn + i*16 + fr)*40 + kq]);
      bl[i] = *reinterpret_cast<const bf16x8v*>(&Bs_l[(wn + i*16 + fr)*40 + kq]);
    }
    #pragma unroll
    for (int i=0;i<4;++i)
      #pragma unroll
      for (int j=0;j<4;++j){
        acc[i][j] = __builtin_amdgcn_mfma_f32_16x16x32_bf16(ah[i], bh[j], acc[i][j], 0,0,0);
        acc[i][j] = __builtin_amdgcn_mfma_f32_16x16x32_bf16(ah[i], bl[j], acc[i][j], 0,0,0);
        acc[i][j] = __builtin_amdgcn_mfma_f32_16x16x32_bf16(al[i], bh[j], acc[i][j], 0,0,0);
      }
    __syncthreads();
  }

  const int cr = (lane >> 4)*4, cc = lane & 15;
  #pragma unroll
  for (int i=0;i<4;++i){
    #pragma unroll
    for (int j=0;j<4;++j){
      #pragma unroll
      for (int rr=0;rr<4;++rr){
        const int gm = m0 + wm + i*16 + cr + rr;
        const int gn = n0 + wn + j*16 + cc;
        if (gm < M && gn < N){
          float v = acc[i][j][rr] * mult;
          if (bias) v += prd(bias, gn, loBias);
          if (relu) v = fmaxf(v, 0.f);
          short* Cp; long ldc, lo; int fl, cn;
          if (nroute > 1 && gn >= r0.nEnd){
            if (nroute > 2 && gn >= r1.nEnd){ Cp=Cb2; ldc=r2.ldc; lo=r2.lo; fl=r2.fl; cn=gn-r1.nEnd; }
            else                            { Cp=Cb1; ldc=r1.ldc; lo=r1.lo; fl=r1.fl; cn=gn-r0.nEnd; }
          } else                            { Cp=Cb0; ldc=r0.ldc; lo=r0.lo; fl=r0.fl; cn=gn; }
          const long idx = (fl & 1) ? ((long)cn*ldc + gm) : ((long)gm*ldc + cn);
          if (fl & 2) v += prd(Cp, idx, lo);
          short h, l; split1(v, h, l);
          Cp[idx] = h; Cp[idx + lo] = l;
        }
      }
    }
  }
}

// =======================================================================
// scores GEMM + fused WAVE-PARALLEL row softmax (+key-mask, +elem mul).
// NN = 128 or 256 (compile-time). Block owns rows m0..m0+127 fully.
// =======================================================================
template<int NN, bool A16>
__global__ __launch_bounds__(256) void gemm_sm(
    const short* __restrict__ Ag, long loA, const short* __restrict__ Bg, long loB,
    int K, long lda, long ldb,
    int nz1, long sA, long sB, long sA2, long sB2,
    float* __restrict__ Sg, long sS, long sS2, int ldS,
    float mult, const int* __restrict__ lengths, int b0,
    const float* __restrict__ mulP, long sMul)
{
  __shared__ short As_h[128*40], As_l[128*40], Bs_h[128*40], Bs_l[128*40];
  const int tid = threadIdx.x;
  const int z1 = blockIdx.z % nz1, z2 = blockIdx.z / nz1;
  const int m0 = blockIdx.y*128;
  const short* A = Ag + z1*sA + z2*sA2;
  const short* B = Bg + z1*sB + z2*sB2;
  float* S = Sg + z1*sS + z2*sS2;

  const int srow = tid >> 1, sc0 = (tid & 1)*16;
  const int lane = tid & 63, wv = tid >> 6;
  const int wm = (wv >> 1)*64, wn = (wv & 1)*64;
  const int fr = lane & 15, kq = (lane >> 4)*8;
  const int cr = (lane >> 4)*4, cc = lane & 15;

  for (int nh = 0; nh < NN; nh += 128){
    RegsP rA, rB;
    ld_pair<A16>(A, loA, lda, 0, K, m0+srow, true, sc0, rA);
    ld_pair<A16>(B, loB, ldb, 0, K, nh+srow, true, sc0, rB);
    f32x4 acc[4][4] = {};
    for (int kb = 0; kb < K; kb += 32){
      wr_pair(rA, As_h, As_l, srow, sc0);
      wr_pair(rB, Bs_h, Bs_l, srow, sc0);
      __syncthreads();
      const int kn = kb + 32;
      if (kn < K){
        ld_pair<A16>(A, loA, lda, kn, K, m0+srow, true, sc0, rA);
        ld_pair<A16>(B, loB, ldb, kn, K, nh+srow, true, sc0, rB);
      }
      bf16x8v ah[4], al[4], bh[4], bl[4];
      #pragma unroll
      for (int i=0;i<4;++i){
        ah[i] = *reinterpret_cast<const bf16x8v*>(&As_h[(wm + i*16 + fr)*40 + kq]);
        al[i] = *reinterpret_cast<const bf16x8v*>(&As_l[(wm + i*16 + fr)*40 + kq]);
        bh[i] = *reinterpret_cast<const bf16x8v*>(&Bs_h[(wn + i*16 + fr)*40 + kq]);
        bl[i] = *reinterpret_cast<const bf16x8v*>(&Bs_l[(wn + i*16 + fr)*40 + kq]);
      }
      #pragma unroll
      for (int i=0;i<4;++i)
        #pragma unroll
        for (int j=0;j<4;++j){
          acc[i][j] = __builtin_amdgcn_mfma_f32_16x16x32_bf16(ah[i], bh[j], acc[i][j], 0,0,0);
          acc[i][j] = __builtin_amdgcn_mfma_f32_16x16x32_bf16(ah[i], bl[j], acc[i][j], 0,0,0);
          acc[i][j] = __builtin_amdgcn_mfma_f32_16x16x32_bf16(al[i], bh[j], acc[i][j], 0,0,0);
        }
      __syncthreads();
    }
    #pragma unroll
    for (int i=0;i<4;++i)
      #pragma unroll
      for (int j=0;j<4;++j)
        #pragma unroll
        for (int rr=0;rr<4;++rr){
          const int gm = m0 + wm + i*16 + cr + rr;
          const int gn = nh + wn + j*16 + cc;
          S[(long)gm*ldS + gn] = acc[i][j][rr] * mult;
        }
  }
  __syncthreads();   // S fully written, block-visible

  // ---- wave-parallel row softmax: wave wv owns rows m0+wv*32 .. +31 ----
  constexpr int CH = NN / 64;               // cols per lane: 2 or 4
  const int cbase = lane*CH;
  int lim = NN;
  if (lengths){ const int L = lengths[b0 + z1]; lim = (L < NN) ? L : NN; }

  float v[CH], vn[CH], mcur[CH], mnxt[CH];
  {
    float* row0 = S + (long)(m0 + wv*32)*ldS + cbase;
    #pragma unroll
    for (int e=0;e<CH;++e) v[e] = row0[e];
    if (mulP){
      const float* mr = mulP + z1*sMul + (long)(m0 + wv*32)*ldS + cbase;
      #pragma unroll
      for (int e=0;e<CH;++e) mcur[e] = mr[e];
    }
  }
  for (int i = 0; i < 32; ++i){
    if (i < 31){
      float* rn = S + (long)(m0 + wv*32 + i + 1)*ldS + cbase;
      #pragma unroll
      for (int e=0;e<CH;++e) vn[e] = rn[e];
      if (mulP){
        const float* mr = mulP + z1*sMul + (long)(m0 + wv*32 + i + 1)*ldS + cbase;
        #pragma unroll
        for (int e=0;e<CH;++e) mnxt[e] = mr[e];
      }
    }
    float mx = -3.0e38f;
    #pragma unroll
    for (int e=0;e<CH;++e) if (cbase+e < lim) mx = fmaxf(mx, v[e]);
    #pragma unroll
    for (int o=32;o>0;o>>=1) mx = fmaxf(mx, __shfl_xor(mx, o, 64));
    float sm = 0.f;
    #pragma unroll
    for (int e=0;e<CH;++e){
      v[e] = (cbase+e < lim) ? __expf(v[e] - mx) : 0.f;
      sm += v[e];
    }
    #pragma unroll
    for (int o=32;o>0;o>>=1) sm += __shfl_xor(sm, o, 64);
    const float inv = 1.f / sm;
    float* row = S + (long)(m0 + wv*32 + i)*ldS + cbase;
    if (mulP){
      #pragma unroll
      for (int e=0;e<CH;++e) row[e] = v[e]*inv*mcur[e];
    } else {
      #pragma unroll
      for (int e=0;e<CH;++e) row[e] = v[e]*inv;
    }
    #pragma unroll
    for (int e=0;e<CH;++e){ v[e] = vn[e]; mcur[e] = mnxt[e]; }
  }
}

// ---------------- hg chunk init (pair out) ----------------
__global__ void build_hg(const void* __restrict__ src, const short* __restrict__ Ru, long loW,
                         short* __restrict__ hg, long loH, const int* __restrict__ flag, int b0){
  const int t = blockIdx.x, bl = blockIdx.y, se = threadIdx.x;  // block 128
  const int f32 = *flag;
  const float s = rdIn(src, ((long)t*B_ + (b0+bl))*(2*SE_) + se, f32);
  const long o = ((long)bl*SE_ + se)*1024 + t*4;
  #pragma unroll
  for (int j=0;j<4;++j){
    const float v = fmaxf(s * prd(Ru, se*4+j, loW), 0.f);
    short h, l; split1(v, h, l);
    hg[o+j] = h; hg[o+j+loH] = l;
  }
}

// ---------------- xx chunk build (pair in/out) ----------------
__global__ void build_xx(const short* __restrict__ hg, long loH,
                         const short* __restrict__ times, long loW,
                         short* __restrict__ xx, long loX, int b0, int G){
  const int blk = blockIdx.x;          // t*G + bl
  const int t = blk / G, bl = blk % G, b = b0 + bl;
  const int tid = threadIdx.x;
  const float tm = prd(times, (long)t*B_ + b, loW);
  for (int c = tid; c < D_MODEL_; c += 256){
    float v;
    if (c < SE_*4){
      v = prd(hg, ((long)bl*SE_ + (c>>2))*1024 + t*4 + (c&3), loH);
    } else {
      const int p = c - SE_*4;
      const int i = p & 7;
      const float ts = exp2f(8.0f * (float)i / 7.0f);
      const float st = tm / ts;
      v = (p < 8) ? sinf(st) : cosf(st);
    }
    short h, l; split1(v, h, l);
    const long o = ((long)t*B_ + b)*D_MODEL_ + c;
    xx[o] = h; xx[o+loX] = l;
  }
}

// ---------------- LN body (row = 528, pairs) ----------------
__device__ __forceinline__ void ln_body_p(short* px, long loX, const short* pr, long loR,
                                          const short* g, const short* bb, long loW, int tid){
  const float x0 = prd(px,tid,loX)     + prd(pr,tid,loR);
  const float x1 = prd(px,tid+256,loX) + prd(pr,tid+256,loR);
  const float x2 = (tid < 16) ? (prd(px,tid+512,loX) + prd(pr,tid+512,loR)) : 0.f;
  __shared__ float rs[256], rq[256];
  rs[tid] = x0 + x1 + x2;
  rq[tid] = x0*x0 + x1*x1 + x2*x2;
  __syncthreads();
  for (int h = 128; h > 0; h >>= 1){
    if (tid < h){ rs[tid] += rs[tid+h]; rq[tid] += rq[tid+h]; }
    __syncthreads();
  }
  const float mean = rs[0] * (1.0f/528.0f);
  const float var  = rq[0] * (1.0f/528.0f) - mean*mean;
  const float inv = rsqrtf(var + 1e-5f);
  short h, l;
  split1((x0-mean)*inv*prd(g,tid,loW) + prd(bb,tid,loW), h, l);
  px[tid] = h; px[tid+loX] = l;
  split1((x1-mean)*inv*prd(g,tid+256,loW) + prd(bb,tid+256,loW), h, l);
  px[tid+256] = h; px[tid+256+loX] = l;
  if (tid < 16){
    split1((x2-mean)*inv*prd(g,tid+512,loW) + prd(bb,tid+512,loW), h, l);
    px[tid+512] = h; px[tid+512+loX] = l;
  }
}

__global__ __launch_bounds__(256) void ln_res_attn(short* __restrict__ xx, long loX,
    const short* __restrict__ res, long loR,
    const short* __restrict__ g, const short* __restrict__ bb, long loW, int b0){
  const int z = blockIdx.x >> 8, t = blockIdx.x & 255;
  short* px = xx + ((long)t*B_ + b0 + z)*D_MODEL_;
  const short* pr = res + (long)blockIdx.x*D_MODEL_;
  ln_body_p(px, loX, pr, loR, g, bb, loW, threadIdx.x);
}

__global__ __launch_bounds__(256) void ln_res_rows(short* __restrict__ xx, long loX,
    const short* __restrict__ res, long loR,
    const short* __restrict__ g, const short* __restrict__ bb, long loW, int r0){
  short* px = xx + ((long)r0 + blockIdx.x)*D_MODEL_;
  const short* pr = res + (long)blockIdx.x*D_MODEL_;
  ln_body_p(px, loX, pr, loR, g, bb, loW, threadIdx.x);
}

// ---------------- masked mean pool (pair in/out) ----------------
__global__ void pool_k(const short* __restrict__ xx, long loX, const int* __restrict__ len,
                       short* __restrict__ pooled, long loP){
  const int b = blockIdx.y;
  const int c = blockIdx.x*256 + threadIdx.x;
  if (c >= D_MODEL_) return;
  const int L = len[b];
  float s = 0.f;
  for (int t = 0; t < L; ++t) s += prd(xx, ((long)t*B_ + b)*D_MODEL_ + c, loX);
  short h, l; split1(s / (float)(L + 1), h, l);
  pooled[(long)b*D_FINAL_ + c] = h;
  pooled[(long)b*D_FINAL_ + c + loP] = l;
}

// ---------------- logits (pair in, out dtype per flag) ----------------
__global__ void logits_k(const short* __restrict__ hid, long loH,
                         const short* __restrict__ W2, const short* __restrict__ b2, long loW,
                         void* __restrict__ out, const int* __restrict__ flag){
  const int z = blockIdx.x;            // b*2 + c
  const int b = z >> 1, c = z & 1;
  const int lane = threadIdx.x;        // 64
  float s = 0.f;
  for (int k = lane; k < D_FINAL_; k += 64)
    s += prd(hid, (long)b*D_FINAL_ + k, loH) * prd(W2, (long)c*D_FINAL_ + k, loW);
  #pragma unroll
  for (int o = 32; o > 0; o >>= 1) s += __shfl_down(s, o, 64);
  if (lane == 0){
    const float r = s + prd(b2, c, loW);
    if (*flag) ((float*)out)[z] = r;
    else       ((bf16*)out)[z] = __float2bfloat16(r);
  }
}

// =======================================================================
// Arena identical to round 7 (peak ~155 MiB, proven cap 167.3 MiB).
// =======================================================================
extern "C" void kernel_launch(void* const* d_in, const int* in_sizes, int n_in,
                              void* d_out, int out_size, void* d_ws, size_t ws_size,
                              hipStream_t stream) {
  const int* lengths = (const int*)d_in[2];
  char* ws = (char*)d_ws;
  const size_t KB = 1024;

  short* wtsH = (short*)ws;
  int* flag = (int*)(ws + 47500*KB);
  short* xxH = (short*)(ws + 48000*KB);
  const long loXX = 17301504;
  char* SC = ws + 115600*KB;

  short* hgA = (short*)(SC + 0*KB);      const long loHG = 2097152;
  short* hgB = (short*)(SC + 8192*KB);
  short* qkc = (short*)(SC + 16384*KB);  const long loQK1 = 4194304;
  short* VtS = (short*)(SC + 32768*KB);  const long loVT1 = 2097152;
  float* S0c = (float*)(SC + 40960*KB);
  float* S1c = (float*)(SC + 41984*KB);
  short* qkb = (short*)(SC + 0*KB);      const long loQK2 = 4325376;
  short* o_c = (short*)(SC + 0*KB);      const long loOC  = 2162688;
  short* pjb = (short*)(SC + 8448*KB);   const long loPJ  = 2162688;
  short* vtb = (short*)(SC + 16896*KB);  const long loVT2 = 2162688;
  float* att = (float*)(SC + 25344*KB);
  short* ff1 = (short*)(SC + 0*KB);      const long loFF  = 4194304;
  short* pj2 = (short*)(SC + 16896*KB);  const long loPJ2 = 4325376;
  short* pooled = (short*)(SC + 0*KB);   const long loPO  = 133120;
  short* hid    = (short*)(SC + 1024*KB);

  CvtTab tb; long cur = 0; int nb = 0; int e = 0;
  auto add = [&](int idx, long so, long n)->long{
    tb.src[e] = d_in[idx]; tb.srcOff[e] = so; tb.dstOff[e] = cur;
    tb.n[e] = (int)n; tb.bstart[e] = nb;
    nb += (int)((n + 255)/256); cur += n; e++;
    return cur - n;
  };
  const long oT  = add(1,0,32768);
  const long oSt = add(3,0,8192);
  const long oRu = add(4,0,512);
  const long oSW = add(5,0,32768);
  const long oSb = add(6,0,512);
  long oQKSV[2], oBQ[2];
  for (int l = 0; l < 2; ++l){
    oQKSV[l] = add(7, (long)l*1048576, 1048576);
    add(8,  (long)l*1048576, 1048576);
    add(13, (long)l*1048576, 1048576);
    add(9,  (long)l*1048576, 1048576);
  }
  for (int l = 0; l < 2; ++l){
    oBQ[l] = add(10, (long)l*1024, 1024);
    add(11, (long)l*1024, 1024);
    add(14, (long)l*1024, 1024);
    add(12, (long)l*1024, 1024);
  }
  const long oWqkv = add(15,0,1672704);
  const long obqkv = add(16,0,3168);
  const long oWo = add(17,0,557568);
  const long obo = add(18,0,1056);
  const long oW1 = add(19,0,135168);
  const long ob1 = add(20,0,256);
  const long oW2 = add(21,0,135168);
  const long ob2 = add(22,0,1056);
  const long og1 = add(23,0,1056);
  const long obb1 = add(24,0,1056);
  const long og2 = add(25,0,1056);
  const long obb2 = add(26,0,1056);
  const long oM1 = add(27,0,1081600);
  const long oM1b = add(28,0,1040);
  const long oM2 = add(29,0,2080);
  const long oM2b = add(30,0,2);
  tb.cnt = e;
  const long loW = (cur + 7) & ~7L;

  detect_k<<<1,256,0,stream>>>(d_in[0], flag);
  cvt_all<<<nb,256,0,stream>>>(tb, wtsH, loW, flag);

  const Route RZ{nullptr,0,0,0,0,0,0};

  // ================= stage 1: propagation (16-batch chunks) =================
  const int G1 = 16;
  for (int b0 = 0; b0 < B_; b0 += G1){
    build_hg<<<dim3(T_, G1), 128, 0, stream>>>(d_in[0], wtsH+oRu, loW, hgA, loHG, flag, b0);
    short* curb = hgA; short* nxtb = hgB;
    for (int l = 0; l < 2; ++l){
      float* S = (l == 0) ? S0c : S1c;
      {
        Route q{qkc, 2048, loQK1, 0, 0, 2048, 0};
        Route s{nxtb, 1024, loHG, 0, 0, 3072, 0};
        Route v{VtS, 2048, loVT1, 0, 0, 4096, 1};
        gemm_s<false,true><<<dim3(32,16,1),256,0,stream>>>(
            curb, loHG, wtsH+oQKSV[l], loW, wtsH+oBQ[l], loW,
            2048, 4096, 1024, 1024, 1024,
            1, 0,0,0,0, 0, 3, q, s, v, 1.f);
      }
      gemm_sm<128,true><<<dim3(1,1,G1),256,0,stream>>>(
          qkc, loQK1, qkc+1024, loQK1,
          1024, 2048, 2048,
          G1, 262144, 262144, 0, 0,
          S, 16384, 0, 128,
          0.03125f, nullptr, 0,
          (l == 1) ? S0c : nullptr, 16384);
      {
        Route c{nxtb, 1024, loHG, 131072, 0, 1024, 2};
        gemm_s<true,true><<<dim3(8,1,G1),256,0,stream>>>(
            S, 0, VtS, loVT1, nullptr, 0,
            128, 1024, 128, 128, 2048,
            G1, 16384, 128, 0, 0, 0, 1, c, RZ, RZ, 1.f);
      }
      short* t_ = curb; curb = nxtb; nxtb = t_;
    }
    build_xx<<<T_*G1,256,0,stream>>>(curb, loHG, wtsH+oT, loW, xxH, loXX, b0, G1);
  }

  // ================= stage 2: transformer (16-batch chunks) =================
  const float iscl = 1.0f / sqrtf((float)HD_);
  const int G2 = 16;
  for (int l = 0; l < 2; ++l){
    const long wqkv = oWqkv + (long)l*836352;
    const long bqkv = obqkv + (long)l*1584;
    for (int b0 = 0; b0 < B_; b0 += G2){
      {
        Route qk{qkb, 1056, loQK2, 270336, 0, 1056, 0};
        Route v{vtb, 256, loVT2, 135168, 0, 1584, 1};
        gemm_s<false,true><<<dim3(13,2,G2),256,0,stream>>>(
            xxH + (long)b0*D_MODEL_, loXX, wtsH+wqkv, loW, wtsH+bqkv, loW,
            256, 1584, 528, (long)B_*D_MODEL_, 528,
            G2, 528, 0, 0, 0, 0, 2, qk, v, RZ, 1.f);
      }
      gemm_sm<256,false><<<dim3(1,2,G2*NH_),256,0,stream>>>(
          qkb, loQK2, qkb+528, loQK2,
          132, 1056, 1056,
          G2, 270336, 270336, 132, 132,
          att, 262144, 65536, 256,
          iscl, lengths, b0, nullptr, 0);
      {
        Route c{o_c, 528, loOC, 135168, 132, HD_, 0};
        gemm_s<true,true><<<dim3(2,2,G2*NH_),256,0,stream>>>(
            att, 0, vtb, loVT2, nullptr, 0,
            256, HD_, 256, 256, 256,
            G2, 262144, 135168, 65536, 33792, 0, 1, c, RZ, RZ, 1.f);
      }
      {
        Route c{pjb, 528, loPJ, 135168, 0, 528, 0};
        gemm_s<false,true><<<dim3(5,2,G2),256,0,stream>>>(
            o_c, loOC, wtsH+oWo+(long)l*278784, loW, wtsH+obo+(long)l*528, loW,
            256, 528, 528, 528, 528,
            G2, 135168, 0, 0, 0, 0, 1, c, RZ, RZ, 1.f);
      }
      ln_res_attn<<<G2*256,256,0,stream>>>(xxH, loXX, pjb, loPJ,
          wtsH+og1+(long)l*528, wtsH+obb1+(long)l*528, loW, b0);
    }
    {
      Route c{ff1, 128, loFF, 0, 0, 128, 0};
      gemm_s<false,true><<<dim3(1,256,1),256,0,stream>>>(
          xxH, loXX, wtsH+oW1+(long)l*67584, loW, wtsH+ob1+(long)l*128, loW,
          32768, 128, 528, 528, 528,
          1, 0,0,0,0, 1, 1, c, RZ, RZ, 1.f);
    }
    for (int r0 = 0; r0 < 32768; r0 += 8192){
      Route c{pj2, 528, loPJ2, 0, 0, 528, 0};
      gemm_s<false,true><<<dim3(5,64,1),256,0,stream>>>(
          ff1 + (long)r0*128, loFF, wtsH+oW2+(long)l*67584, loW, wtsH+ob2+(long)l*528, loW,
          8192, 528, 128, 128, 128,
          1, 0,0,0,0, 0, 1, c, RZ, RZ, 1.f);
      ln_res_rows<<<8192,256,0,stream>>>(xxH, loXX, pj2, loPJ2,
          wtsH+og2+(long)l*528, wtsH+obb2+(long)l*528, loW, r0);
    }
  }

  // ================= stage 3: pool + MLP head =================
  pool_k<<<dim3(3,B_),256,0,stream>>>(xxH, loXX, lengths, pooled, loPO);
  {
    Route c{pooled + D_MODEL_, 1040, loPO, 0, 0, 512, 0};
    gemm_s<false,true><<<dim3(4,1,1),256,0,stream>>>(
        wtsH+oSt, loW, wtsH+oSW, loW, wtsH+oSb, loW,
        128, 512, 64, 64, 64,
        1, 0,0,0,0, 0, 1, c, RZ, RZ, 1.f);
  }
  {
    Route c{hid, 1040, loPO, 0, 0, 1040, 0};
    gemm_s<false,true><<<dim3(9,1,1),256,0,stream>>>(
        pooled, loPO, wtsH+oM1, loW, wtsH+oM1b, loW,
        128, 1040, 1040, 1040, 1040,
        1, 0,0,0,0, 1, 1, c, RZ, RZ, 1.f);
  }
  logits_k<<<B_*2,64,0,stream>>>(hid, loPO, wtsH+oM2, wtsH+oM2b, loW, d_out, flag);
}